// Round 14
// baseline (426.291 us; speedup 1.0000x reference)
//
#include <hip/hip_runtime.h>
#include <math.h>

#define NN 50000
#define EE 500000
#define HH 128
#define NHEADS 3
#define CC 10
#define GG 64
#define EPSV 1e-5f
#define SLOPE 0.2f

typedef __attribute__((ext_vector_type(8))) short short8;
typedef __attribute__((ext_vector_type(4))) float f32x4;
typedef __attribute__((ext_vector_type(2))) float f32x2;

// ---------------- bf16 helpers (RNE) ----------------

__device__ __forceinline__ unsigned short f2b(float x) {
    unsigned int u = __builtin_bit_cast(unsigned int, x);
    return (unsigned short)((u + 0x7fffu + ((u >> 16) & 1u)) >> 16);
}
__device__ __forceinline__ unsigned int pack2(float a, float b) {
    return (unsigned int)f2b(a) | ((unsigned int)f2b(b) << 16);
}
__device__ __forceinline__ float2 b2f2(unsigned int u) {
    float2 r;
    r.x = __builtin_bit_cast(float, u << 16);
    r.y = __builtin_bit_cast(float, u & 0xffff0000u);
    return r;
}

// ---------------- fused zero-init ----------------

__global__ void k_zero(int* __restrict__ deg, float* __restrict__ bn1,
                       float* __restrict__ bn_sums23, float* __restrict__ poolacc) {
    int i = blockIdx.x * 256 + threadIdx.x;
    if (i < NN) deg[i] = 0;
    if (i < 256) bn1[i] = 0.f;
    if (i < 512) bn_sums23[i] = 0.f;
    if (i < GG * 128 + GG) poolacc[i] = 0.f;
}

// ---------------- CSR build ----------------

__global__ void k_count_deg(const int* __restrict__ ei, int* __restrict__ deg) {
    int e = blockIdx.x * 256 + threadIdx.x;
    if (e < EE) atomicAdd(&deg[ei[EE + e]], 1);
}

__global__ void k_scan1(const int* __restrict__ deg, int* __restrict__ row_start,
                        int* __restrict__ blk) {
    __shared__ int s[256];
    int i = blockIdx.x * 256 + threadIdx.x;
    int v = (i < NN) ? deg[i] : 0;
    s[threadIdx.x] = v;
    __syncthreads();
    for (int o = 1; o < 256; o <<= 1) {
        int t = (threadIdx.x >= o) ? s[threadIdx.x - o] : 0;
        __syncthreads();
        s[threadIdx.x] += t;
        __syncthreads();
    }
    if (i < NN) row_start[i] = s[threadIdx.x] - v;
    if (threadIdx.x == 255) blk[blockIdx.x] = s[255];
}

__global__ void k_scan2(int* __restrict__ blk, int nb) {
    __shared__ int s[256];
    int v = (threadIdx.x < nb) ? blk[threadIdx.x] : 0;
    s[threadIdx.x] = v;
    __syncthreads();
    for (int o = 1; o < 256; o <<= 1) {
        int t = (threadIdx.x >= o) ? s[threadIdx.x - o] : 0;
        __syncthreads();
        s[threadIdx.x] += t;
        __syncthreads();
    }
    if (threadIdx.x < nb) blk[threadIdx.x] = s[threadIdx.x] - v;
}

__global__ void k_scan3(int* __restrict__ row_start, const int* __restrict__ blk,
                        const int* __restrict__ deg, int* __restrict__ cursor,
                        float* __restrict__ dinv, float* __restrict__ inv_sage) {
    int i = blockIdx.x * 256 + threadIdx.x;
    if (i < NN) {
        int rs = row_start[i] + blk[blockIdx.x];
        row_start[i] = rs;
        cursor[i] = rs;
        int d = deg[i];
        dinv[i] = rsqrtf((float)(d + 1));
        inv_sage[i] = 1.0f / (float)(d > 1 ? d : 1);
    }
}

__global__ void k_fill(const int* __restrict__ ei, int* __restrict__ cursor,
                       int* __restrict__ csr_src) {
    int e = blockIdx.x * 256 + threadIdx.x;
    if (e < EE) {
        int d = ei[EE + e];
        int p = atomicAdd(&cursor[d], 1);
        csr_src[p] = ei[e];
    }
}

// ---------------- fused weight prep ----------------

__device__ __forceinline__ void split_store(float x, size_t dst, short* hi, short* lo) {
    unsigned int ux = __builtin_bit_cast(unsigned int, x);
    unsigned short hx = (unsigned short)(ux >> 16);
    float fx = __builtin_bit_cast(float, ux & 0xffff0000u);
    unsigned short lx = (unsigned short)(__builtin_bit_cast(unsigned int, x - fx) >> 16);
    hi[dst] = (short)hx;
    lo[dst] = (short)lx;
}

__device__ __forceinline__ void prep_one(float x, int k, int n, int cBase,
                                         short* hi, short* lo) {
    int c = (k >> 6) + cBase;
    int s = (k >> 5) & 1, quad = (k >> 3) & 3, j = k & 7;
    int G = n >> 4, l = quad * 16 + (n & 15);
    size_t dst = ((((size_t)(c * 2 + s)) * 8 + G) * 64 + l) * 8 + j;
    split_store(x, dst, hi, lo);
}

__global__ void k_prep_all(const float* __restrict__ W1, const float* __restrict__ Wl,
                           const float* __restrict__ Wr, const float* __restrict__ W3,
                           const float* __restrict__ att_src, const float* __restrict__ att_dst,
                           short* __restrict__ w1hi, short* __restrict__ w1lo,
                           short* __restrict__ wshi, short* __restrict__ wslo,
                           short* __restrict__ w3hi, short* __restrict__ w3lo,
                           float* __restrict__ wsrc, float* __restrict__ wdst) {
    int b = blockIdx.x, tid = threadIdx.x;
    if (b < 64) {
        int i = b * 256 + tid;
        prep_one(W1[i], i >> 7, i & 127, 0, w1hi, w1lo);
    } else if (b < 128) {
        int i = (b - 64) * 256 + tid;
        prep_one(Wl[i], i >> 7, i & 127, 0, wshi, wslo);
    } else if (b < 192) {
        int i = (b - 128) * 256 + tid;
        prep_one(Wr[i], i >> 7, i & 127, 2, wshi, wslo);
    } else if (b < 384) {
        int i = (b - 192) * 256 + tid;
        int k = i >> 7, n = i & 127;
        int h = k >> 7, kk = k & 127;
        float x = W3[(size_t)kk * 384 + h * 128 + n] * (1.f / 3.f);
        prep_one(x, k, n, 0, w3hi, w3lo);
    } else {
        for (int e = tid; e < 384; e += 256) {
            int h = e >> 7, k = e & 127;
            float s1 = 0.f, s2 = 0.f;
            const float* wrow = W3 + (size_t)k * 384 + h * 128;
            const float* as = att_src + h * 128;
            const float* ad = att_dst + h * 128;
            for (int j = 0; j < 128; j++) {
                float wv = wrow[j];
                s1 += wv * as[j];
                s2 += wv * ad[j];
            }
            wsrc[e] = s1;
            wdst[e] = s2;
        }
    }
}

// ---------------- MFMA GEMM  C = [A1|A2] @ B + bias  (BM=64, + optional stats) ---

template <bool ABF16, bool OUTB, bool STATS>
__global__ __launch_bounds__(256) void k_gemm_mfma(
    const void* __restrict__ A1v, const void* __restrict__ A2v,
    const short* __restrict__ Bhi, const short* __restrict__ Blo,
    const float* __restrict__ bias, void* __restrict__ Cv,
    float* __restrict__ sums, int M, int kc1, int kcT, int strideA1) {
    __shared__ short Ahi[64 * 72];
    __shared__ short Alo[ABF16 ? 8 : 64 * 72];
    __shared__ float cs[256];
    int tid = threadIdx.x;
    int rBase = blockIdx.x * 64;
    int wv = tid >> 6, lane = tid & 63;
    int rowHalf = wv >> 1, colHalf = wv & 1;  // rows 32/wave, cols 64/wave
    int quad = lane >> 4, l15 = lane & 15;

    f32x4 acc[2][4];
#pragma unroll
    for (int a = 0; a < 2; a++)
#pragma unroll
        for (int b = 0; b < 4; b++) acc[a][b] = (f32x4)(0.f);

    for (int c = 0; c < kcT; c++) {
        const void* Asrc;
        int kOff, strideA;
        if (c < kc1) { Asrc = A1v; kOff = c * 64; strideA = strideA1; }
        else { Asrc = A2v; kOff = (c - kc1) * 64; strideA = 128; }

        __syncthreads();
        if (ABF16) {
            const unsigned short* As = (const unsigned short*)Asrc;
#pragma unroll
            for (int q = 0; q < 2; q++) {
                int slot = q * 256 + tid;
                int r = slot >> 3, k8 = slot & 7;
                uint4 v = make_uint4(0, 0, 0, 0);
                int gr = rBase + r;
                if (gr < M) v = *(const uint4*)(As + (size_t)gr * strideA + kOff + k8 * 8);
                *(uint4*)(Ahi + r * 72 + k8 * 8) = v;
            }
        } else {
            const float* As = (const float*)Asrc;
#pragma unroll
            for (int q8 = 0; q8 < 4; q8++) {
                int slot = q8 * 256 + tid;
                int r = slot >> 4, k4 = slot & 15;
                float4 v = make_float4(0.f, 0.f, 0.f, 0.f);
                int gr = rBase + r;
                if (gr < M) v = *(const float4*)(As + (size_t)gr * strideA + kOff + k4 * 4);
                unsigned int ux = __builtin_bit_cast(unsigned int, v.x);
                unsigned int uy = __builtin_bit_cast(unsigned int, v.y);
                unsigned int uz = __builtin_bit_cast(unsigned int, v.z);
                unsigned int uw = __builtin_bit_cast(unsigned int, v.w);
                unsigned int hx = ux >> 16, hy = uy >> 16, hz = uz >> 16, hw = uw >> 16;
                float fx = __builtin_bit_cast(float, ux & 0xffff0000u);
                float fy = __builtin_bit_cast(float, uy & 0xffff0000u);
                float fz = __builtin_bit_cast(float, uz & 0xffff0000u);
                float fw = __builtin_bit_cast(float, uw & 0xffff0000u);
                unsigned int lx = __builtin_bit_cast(unsigned int, v.x - fx) >> 16;
                unsigned int ly = __builtin_bit_cast(unsigned int, v.y - fy) >> 16;
                unsigned int lz = __builtin_bit_cast(unsigned int, v.z - fz) >> 16;
                unsigned int lw = __builtin_bit_cast(unsigned int, v.w - fw) >> 16;
                uint2 ph = make_uint2(hx | (hy << 16), hz | (hw << 16));
                uint2 pl = make_uint2(lx | (ly << 16), lz | (lw << 16));
                *(uint2*)(Ahi + r * 72 + k4 * 4) = ph;
                *(uint2*)(Alo + r * 72 + k4 * 4) = pl;
            }
        }
        __syncthreads();

#pragma unroll
        for (int s = 0; s < 2; s++) {
            short8 ah[2], al[2];
#pragma unroll
            for (int rb = 0; rb < 2; rb++) {
                int m = rowHalf * 32 + rb * 16 + l15;
                ah[rb] = *(const short8*)(Ahi + m * 72 + s * 32 + quad * 8);
                if (!ABF16) al[rb] = *(const short8*)(Alo + m * 72 + s * 32 + quad * 8);
            }
#pragma unroll
            for (int cg = 0; cg < 4; cg++) {
                int G = colHalf * 4 + cg;
                size_t bo = ((((size_t)(c * 2 + s)) * 8 + G) * 64 + lane) * 8;
                short8 bh = *(const short8*)(Bhi + bo);
                short8 bl = *(const short8*)(Blo + bo);
#pragma unroll
                for (int rb = 0; rb < 2; rb++) {
                    acc[rb][cg] = __builtin_amdgcn_mfma_f32_16x16x32_bf16(ah[rb], bh, acc[rb][cg], 0, 0, 0);
                    if (!ABF16)
                        acc[rb][cg] = __builtin_amdgcn_mfma_f32_16x16x32_bf16(al[rb], bh, acc[rb][cg], 0, 0, 0);
                    acc[rb][cg] = __builtin_amdgcn_mfma_f32_16x16x32_bf16(ah[rb], bl, acc[rb][cg], 0, 0, 0);
                }
            }
        }
    }

    if (STATS) {
        cs[tid] = 0.f;
        __syncthreads();
    }

#pragma unroll
    for (int cg = 0; cg < 4; cg++) {
        int col = colHalf * 64 + cg * 16 + l15;
        float bv = bias ? bias[col] : 0.f;
        float ps = 0.f, pq = 0.f;
#pragma unroll
        for (int rb = 0; rb < 2; rb++) {
#pragma unroll
            for (int r = 0; r < 4; r++) {
                int row = rBase + rowHalf * 32 + rb * 16 + quad * 4 + r;
                if (row < M) {
                    float ov = acc[rb][cg][r] + bv;
                    if (OUTB) ((unsigned short*)Cv)[(size_t)row * HH + col] = f2b(ov);
                    else ((float*)Cv)[(size_t)row * HH + col] = ov;
                    if (STATS) { ps += ov; pq += ov * ov; }
                }
            }
        }
        if (STATS) {
            ps += __shfl_xor(ps, 16, 64); ps += __shfl_xor(ps, 32, 64);
            pq += __shfl_xor(pq, 16, 64); pq += __shfl_xor(pq, 32, 64);
            if (quad == 0) {
                atomicAdd(&cs[col], ps);
                atomicAdd(&cs[128 + col], pq);
            }
        }
    }
    if (STATS) {
        __syncthreads();
        atomicAdd(&sums[tid], cs[tid]);
    }
}

// ---------------- GCN aggregation (4 nodes/wave, 16 lanes each, uint4 loads) -----

__global__ void k_gcn_agg(const unsigned int* __restrict__ hb, const int* __restrict__ row_start,
                          const int* __restrict__ deg, const int* __restrict__ csr,
                          const float* __restrict__ dinv, const float* __restrict__ b1,
                          unsigned int* __restrict__ outb) {
    int tid = threadIdx.x;
    int n = blockIdx.x * 16 + (tid >> 4);  // 16 nodes/block
    if (n >= NN) return;
    int l = tid & 15;
    const uint4* hb4 = (const uint4*)hb;
    float di = dinv[n];
    float wsq = di * di;
    uint4 hv4 = hb4[(size_t)n * 16 + l];
    float2 p0 = b2f2(hv4.x), p1 = b2f2(hv4.y), p2 = b2f2(hv4.z), p3 = b2f2(hv4.w);
    float acc[8] = {p0.x * wsq, p0.y * wsq, p1.x * wsq, p1.y * wsq,
                    p2.x * wsq, p2.y * wsq, p3.x * wsq, p3.y * wsq};
    int s0 = row_start[n], cnt = deg[n];
    int i = 0;
    for (; i + 4 <= cnt; i += 4) {
        int ss[4]; float ww[4]; uint4 vv[4];
#pragma unroll
        for (int j = 0; j < 4; j++) ss[j] = csr[s0 + i + j];
#pragma unroll
        for (int j = 0; j < 4; j++) { ww[j] = dinv[ss[j]]; vv[j] = hb4[(size_t)ss[j] * 16 + l]; }
#pragma unroll
        for (int j = 0; j < 4; j++) {
            float wj = ww[j] * di;
            float2 q0 = b2f2(vv[j].x), q1 = b2f2(vv[j].y), q2 = b2f2(vv[j].z), q3 = b2f2(vv[j].w);
            acc[0] += q0.x * wj; acc[1] += q0.y * wj;
            acc[2] += q1.x * wj; acc[3] += q1.y * wj;
            acc[4] += q2.x * wj; acc[5] += q2.y * wj;
            acc[6] += q3.x * wj; acc[7] += q3.y * wj;
        }
    }
    for (; i < cnt; i++) {
        int s = csr[s0 + i];
        float wj = dinv[s] * di;
        uint4 v = hb4[(size_t)s * 16 + l];
        float2 q0 = b2f2(v.x), q1 = b2f2(v.y), q2 = b2f2(v.z), q3 = b2f2(v.w);
        acc[0] += q0.x * wj; acc[1] += q0.y * wj;
        acc[2] += q1.x * wj; acc[3] += q1.y * wj;
        acc[4] += q2.x * wj; acc[5] += q2.y * wj;
        acc[6] += q3.x * wj; acc[7] += q3.y * wj;
    }
    float4 bb0 = *(const float4*)(b1 + l * 8);
    float4 bb1 = *(const float4*)(b1 + l * 8 + 4);
    uint4 o;
    o.x = pack2(acc[0] + bb0.x, acc[1] + bb0.y);
    o.y = pack2(acc[2] + bb0.z, acc[3] + bb0.w);
    o.z = pack2(acc[4] + bb1.x, acc[5] + bb1.y);
    o.w = pack2(acc[6] + bb1.z, acc[7] + bb1.w);
    ((uint4*)outb)[(size_t)n * 16 + l] = o;
}

// ---------------- BN stats over bf16 array (separate, cheap) ----------------

__global__ void k_bn_stats_b(const unsigned int* __restrict__ hb, float* __restrict__ sums) {
    int f = threadIdx.x;  // 128 threads, feature f
    int rows_per = (NN + gridDim.x - 1) / gridDim.x;
    int r0 = blockIdx.x * rows_per;
    int r1 = r0 + rows_per;
    if (r1 > NN) r1 = NN;
    int wi = f >> 1, hi = f & 1;
    float s = 0.f, sq = 0.f;
    for (int r = r0; r < r1; r++) {
        float2 vv = b2f2(hb[(size_t)r * 64 + wi]);
        float v = hi ? vv.y : vv.x;
        s += v;
        sq += v * v;
    }
    atomicAdd(&sums[f], s);
    atomicAdd(&sums[128 + f], sq);
}

// ---------------- SAGE aggregation (4 nodes/wave, 16 lanes each, uint4 loads) ----

__global__ void k_sage_agg(const unsigned int* __restrict__ hb, const int* __restrict__ row_start,
                           const int* __restrict__ deg, const int* __restrict__ csr,
                           const float* __restrict__ inv_sage, unsigned int* __restrict__ outb) {
    int tid = threadIdx.x;
    int n = blockIdx.x * 16 + (tid >> 4);
    if (n >= NN) return;
    int l = tid & 15;
    const uint4* hb4 = (const uint4*)hb;
    float acc[8] = {0.f, 0.f, 0.f, 0.f, 0.f, 0.f, 0.f, 0.f};
    int s0 = row_start[n], cnt = deg[n];
    int i = 0;
    for (; i + 4 <= cnt; i += 4) {
        int ss[4]; uint4 vv[4];
#pragma unroll
        for (int j = 0; j < 4; j++) ss[j] = csr[s0 + i + j];
#pragma unroll
        for (int j = 0; j < 4; j++) vv[j] = hb4[(size_t)ss[j] * 16 + l];
#pragma unroll
        for (int j = 0; j < 4; j++) {
            float2 q0 = b2f2(vv[j].x), q1 = b2f2(vv[j].y), q2 = b2f2(vv[j].z), q3 = b2f2(vv[j].w);
            acc[0] += q0.x; acc[1] += q0.y;
            acc[2] += q1.x; acc[3] += q1.y;
            acc[4] += q2.x; acc[5] += q2.y;
            acc[6] += q3.x; acc[7] += q3.y;
        }
    }
    for (; i < cnt; i++) {
        uint4 v = hb4[(size_t)csr[s0 + i] * 16 + l];
        float2 q0 = b2f2(v.x), q1 = b2f2(v.y), q2 = b2f2(v.z), q3 = b2f2(v.w);
        acc[0] += q0.x; acc[1] += q0.y;
        acc[2] += q1.x; acc[3] += q1.y;
        acc[4] += q2.x; acc[5] += q2.y;
        acc[6] += q3.x; acc[7] += q3.y;
    }
    float sc = inv_sage[n];
    uint4 o;
    o.x = pack2(acc[0] * sc, acc[1] * sc);
    o.y = pack2(acc[2] * sc, acc[3] * sc);
    o.z = pack2(acc[4] * sc, acc[5] * sc);
    o.w = pack2(acc[6] * sc, acc[7] * sc);
    ((uint4*)outb)[(size_t)n * 16 + l] = o;
}

// ---------------- GAT: fused softmax + aggregation (2 nodes/wave, fp8, pk-fma) ---

__device__ __forceinline__ float lrelu(float a) { return fmaxf(a, SLOPE * a); }

__global__ void k_gat_fused(const unsigned int* __restrict__ h8u, const int* __restrict__ row_start,
                            const int* __restrict__ deg, const int* __restrict__ csr,
                            const float4* __restrict__ asrc4, const float4* __restrict__ adst4,
                            float4* __restrict__ alphaE, unsigned int* __restrict__ aggb) {
    int tid = threadIdx.x;
    int wv = tid >> 6, lane = tid & 63;
    int half = lane >> 5, l = lane & 31;       // 32 lanes per node
    int n = blockIdx.x * 8 + wv * 2 + half;
    if (n >= NN) return;
    float4 ad = adst4[n], asv = asrc4[n];
    float es0 = lrelu(asv.x + ad.x), es1 = lrelu(asv.y + ad.y), es2 = lrelu(asv.z + ad.z);
    int s0 = row_start[n], cnt = deg[n];
    float self0, self1, self2;
    unsigned int pk1 = 0, pk2 = 0;
    bool fast = (cnt <= 32);
    if (fast) {
        bool valid = l < cnt;
        int sReg = 0;
        float e0 = -3e38f, e1 = -3e38f, e2 = -3e38f;
        if (valid) {
            sReg = csr[s0 + l];
            float4 a4 = asrc4[sReg];
            e0 = lrelu(a4.x + ad.x); e1 = lrelu(a4.y + ad.y); e2 = lrelu(a4.z + ad.z);
        }
        float M0 = e0, M1 = e1, M2 = e2;
#pragma unroll
        for (int o = 16; o > 0; o >>= 1) {
            M0 = fmaxf(M0, __shfl_xor(M0, o, 64));
            M1 = fmaxf(M1, __shfl_xor(M1, o, 64));
            M2 = fmaxf(M2, __shfl_xor(M2, o, 64));
        }
        float m0 = fmaxf(es0, M0), m1 = fmaxf(es1, M1), m2 = fmaxf(es2, M2);
        float w0 = valid ? __expf(e0 - m0) : 0.f;
        float w1 = valid ? __expf(e1 - m1) : 0.f;
        float w2 = valid ? __expf(e2 - m2) : 0.f;
        float S0 = w0, S1 = w1, S2 = w2;
#pragma unroll
        for (int o = 16; o > 0; o >>= 1) {
            S0 += __shfl_xor(S0, o, 64);
            S1 += __shfl_xor(S1, o, 64);
            S2 += __shfl_xor(S2, o, 64);
        }
        float sw0 = __expf(es0 - m0), sw1 = __expf(es1 - m1), sw2 = __expf(es2 - m2);
        float r0 = 1.f / (S0 + sw0), r1 = 1.f / (S1 + sw1), r2 = 1.f / (S2 + sw2);
        pk1 = ((unsigned int)sReg & 0xffffu) | ((unsigned int)f2b(w2 * r2) << 16);
        pk2 = pack2(w0 * r0, w1 * r1);
        self0 = sw0 * r0; self1 = sw1 * r1; self2 = sw2 * r2;
    } else {
        float m0 = es0, m1 = es1, m2 = es2;
        for (int base = 0; base < cnt; base += 32) {
            int i2 = base + l;
            float e0 = -3e38f, e1 = -3e38f, e2 = -3e38f;
            if (i2 < cnt) {
                int s = csr[s0 + i2];
                float4 a4 = asrc4[s];
                e0 = lrelu(a4.x + ad.x); e1 = lrelu(a4.y + ad.y); e2 = lrelu(a4.z + ad.z);
                alphaE[s0 + i2] = make_float4(e0, e1, e2, 0.f);
            }
#pragma unroll
            for (int o = 16; o > 0; o >>= 1) {
                e0 = fmaxf(e0, __shfl_xor(e0, o, 64));
                e1 = fmaxf(e1, __shfl_xor(e1, o, 64));
                e2 = fmaxf(e2, __shfl_xor(e2, o, 64));
            }
            m0 = fmaxf(m0, e0); m1 = fmaxf(m1, e1); m2 = fmaxf(m2, e2);
        }
        float l0 = __expf(es0 - m0), l1 = __expf(es1 - m1), l2 = __expf(es2 - m2);
        for (int base = 0; base < cnt; base += 32) {
            int i2 = base + l;
            float w0 = 0.f, w1 = 0.f, w2 = 0.f;
            if (i2 < cnt) {
                float4 e = alphaE[s0 + i2];
                w0 = __expf(e.x - m0); w1 = __expf(e.y - m1); w2 = __expf(e.z - m2);
            }
#pragma unroll
            for (int o = 16; o > 0; o >>= 1) {
                w0 += __shfl_xor(w0, o, 64);
                w1 += __shfl_xor(w1, o, 64);
                w2 += __shfl_xor(w2, o, 64);
            }
            l0 += w0; l1 += w1; l2 += w2;
        }
        float r0 = 1.f / l0, r1 = 1.f / l1, r2 = 1.f / l2;
        self0 = __expf(es0 - m0) * r0;
        self1 = __expf(es1 - m1) * r1;
        self2 = __expf(es2 - m2) * r2;
        for (int base = 0; base < cnt; base += 32) {
            int i2 = base + l;
            if (i2 < cnt) {
                float4 e = alphaE[s0 + i2];
                alphaE[s0 + i2] = make_float4(__expf(e.x - m0) * r0, __expf(e.y - m1) * r1,
                                              __expf(e.z - m2) * r2, 0.f);
            }
        }
    }

    // phase 2: aggregation — lane l covers 4 fp8 features (uint), pk-fma math
    unsigned int hvu = h8u[(size_t)n * 32 + l];
    f32x2 v01 = __builtin_amdgcn_cvt_pk_f32_fp8((int)hvu, false);
    f32x2 v23 = __builtin_amdgcn_cvt_pk_f32_fp8((int)hvu, true);
    f32x2 a0l = v01 * self0, a0h = v23 * self0;
    f32x2 a1l = v01 * self1, a1h = v23 * self1;
    f32x2 a2l = v01 * self2, a2h = v23 * self2;
    int lbase = half << 5;
    if (fast) {
        int i = 0;
        for (; i + 4 <= cnt; i += 4) {
            unsigned int q1[4], q2[4], uu[4];
#pragma unroll
            for (int j = 0; j < 4; j++) {
                q1[j] = __shfl(pk1, lbase + i + j, 64);
                q2[j] = __shfl(pk2, lbase + i + j, 64);
            }
#pragma unroll
            for (int j = 0; j < 4; j++) uu[j] = h8u[(size_t)(q1[j] & 0xffffu) * 32 + l];
#pragma unroll
            for (int j = 0; j < 4; j++) {
                f32x2 w01 = __builtin_amdgcn_cvt_pk_f32_fp8((int)uu[j], false);
                f32x2 w23 = __builtin_amdgcn_cvt_pk_f32_fp8((int)uu[j], true);
                float2 a01 = b2f2(q2[j]);
                float w2 = __builtin_bit_cast(float, q1[j] & 0xffff0000u);
                a0l += a01.x * w01; a0h += a01.x * w23;
                a1l += a01.y * w01; a1h += a01.y * w23;
                a2l += w2 * w01;    a2h += w2 * w23;
            }
        }
        for (; i < cnt; i++) {
            unsigned int q1 = __shfl(pk1, lbase + i, 64);
            unsigned int q2 = __shfl(pk2, lbase + i, 64);
            unsigned int u = h8u[(size_t)(q1 & 0xffffu) * 32 + l];
            f32x2 w01 = __builtin_amdgcn_cvt_pk_f32_fp8((int)u, false);
            f32x2 w23 = __builtin_amdgcn_cvt_pk_f32_fp8((int)u, true);
            float2 a01 = b2f2(q2);
            float w2 = __builtin_bit_cast(float, q1 & 0xffff0000u);
            a0l += a01.x * w01; a0h += a01.x * w23;
            a1l += a01.y * w01; a1h += a01.y * w23;
            a2l += w2 * w01;    a2h += w2 * w23;
        }
    } else {
        for (int i = 0; i < cnt; i++) {
            int s = csr[s0 + i];
            float4 al = alphaE[s0 + i];
            unsigned int u = h8u[(size_t)s * 32 + l];
            f32x2 w01 = __builtin_amdgcn_cvt_pk_f32_fp8((int)u, false);
            f32x2 w23 = __builtin_amdgcn_cvt_pk_f32_fp8((int)u, true);
            a0l += al.x * w01; a0h += al.x * w23;
            a1l += al.y * w01; a1h += al.y * w23;
            a2l += al.z * w01; a2h += al.z * w23;
        }
    }
    unsigned int* op = aggb + (size_t)n * 192 + 2 * l;
    *(uint2*)(op) = make_uint2(pack2(a0l.x, a0l.y), pack2(a0h.x, a0h.y));
    *(uint2*)(op + 64) = make_uint2(pack2(a1l.x, a1l.y), pack2(a1h.x, a1h.y));
    *(uint2*)(op + 128) = make_uint2(pack2(a2l.x, a2l.y), pack2(a2h.x, a2h.y));
}

// ---------------- BatchNorm + ELU ----------------

__device__ __forceinline__ float elu1(float x) { return x > 0.f ? x : (__expf(x) - 1.f); }

__device__ __forceinline__ float4 bn_apply4(float4 v, const float* sums,
                                            const float* gamma, const float* beta, int f4) {
    const float invN = 1.0f / NN;
    float4 s4 = *(const float4*)(sums + f4);
    float4 q4 = *(const float4*)(sums + 128 + f4);
    float4 g4 = *(const float4*)(gamma + f4);
    float4 b4 = *(const float4*)(beta + f4);
    float mx = s4.x * invN, my = s4.y * invN, mz = s4.z * invN, mw = s4.w * invN;
    float scx = rsqrtf(q4.x * invN - mx * mx + EPSV) * g4.x;
    float scy = rsqrtf(q4.y * invN - my * my + EPSV) * g4.y;
    float scz = rsqrtf(q4.z * invN - mz * mz + EPSV) * g4.z;
    float scw = rsqrtf(q4.w * invN - mw * mw + EPSV) * g4.w;
    v.x = elu1(v.x * scx + (b4.x - mx * scx));
    v.y = elu1(v.y * scy + (b4.y - my * scy));
    v.z = elu1(v.z * scz + (b4.z - mz * scz));
    v.w = elu1(v.w * scw + (b4.w - mw * scw));
    return v;
}

// layer-1: bf16 in, bf16 out
__global__ void k_bn_elu_b(const unsigned int* __restrict__ hpre, const float* __restrict__ sums,
                           const float* __restrict__ gamma, const float* __restrict__ beta,
                           unsigned int* __restrict__ hb) {
    int i = blockIdx.x * 256 + threadIdx.x;  // NN*32
    int f4 = (i & 31) << 2;
    uint2 p = *(const uint2*)(hpre + (size_t)(i >> 5) * 64 + (i & 31) * 2);
    float2 v01 = b2f2(p.x), v23 = b2f2(p.y);
    float4 v = make_float4(v01.x, v01.y, v23.x, v23.y);
    v = bn_apply4(v, sums, gamma, beta, f4);
    uint2 q = make_uint2(pack2(v.x, v.y), pack2(v.z, v.w));
    *(uint2*)(hb + (size_t)(i >> 5) * 64 + (i & 31) * 2) = q;
}

// layer-2 variant: fp32 in, fp8 out + attention logits
__global__ void k_bn_elu_att(const float* __restrict__ h, const float* __restrict__ sums,
                             const float* __restrict__ gamma, const float* __restrict__ beta,
                             const float* __restrict__ wsrc, const float* __restrict__ wdst,
                             unsigned int* __restrict__ h8w, float4* __restrict__ asrc4,
                             float4* __restrict__ adst4) {
    int i = blockIdx.x * 256 + threadIdx.x;
    int fi = i & 31;
    int f4 = fi << 2;
    float4 v = bn_apply4(((const float4*)h)[i], sums, gamma, beta, f4);
    int p8 = __builtin_amdgcn_cvt_pk_fp8_f32(v.x, v.y, 0, false);
    p8 = __builtin_amdgcn_cvt_pk_fp8_f32(v.z, v.w, p8, true);
    h8w[(size_t)(i >> 5) * 32 + fi] = (unsigned int)p8;
    const float4* ws4 = (const float4*)wsrc;
    const float4* wd4 = (const float4*)wdst;
    float d[6];
#pragma unroll
    for (int hd = 0; hd < 3; hd++) {
        float4 a = ws4[hd * 32 + fi];
        float4 b = wd4[hd * 32 + fi];
        d[hd] = v.x * a.x + v.y * a.y + v.z * a.z + v.w * a.w;
        d[3 + hd] = v.x * b.x + v.y * b.y + v.z * b.z + v.w * b.w;
    }
#pragma unroll
    for (int o = 16; o > 0; o >>= 1) {
#pragma unroll
        for (int j = 0; j < 6; j++) d[j] += __shfl_xor(d[j], o, 64);
    }
    if ((threadIdx.x & 31) == 0) {
        int r = i >> 5;
        asrc4[r] = make_float4(d[0], d[1], d[2], 0.f);
        adst4[r] = make_float4(d[3], d[4], d[5], 0.f);
    }
}

// ---------------- Pool (BN+ELU fused, bf16 input) + classifier ----------------

#define POOL_BLOCKS 800

__global__ void k_pool_bn(const unsigned int* __restrict__ hb, const int* __restrict__ batch,
                          const float* __restrict__ sums, const float* __restrict__ gamma,
                          const float* __restrict__ beta, float* __restrict__ pool,
                          float* __restrict__ cntf) {
    const int RP = (NN + POOL_BLOCKS - 1) / POOL_BLOCKS;
    int r0 = blockIdx.x * RP;
    int r1 = r0 + RP;
    if (r1 > NN) r1 = NN;
    if (r0 >= r1) return;
    int f = threadIdx.x;
    const float invN = 1.0f / NN;
    float mu = sums[f] * invN;
    float var = sums[128 + f] * invN - mu * mu;
    float sc = rsqrtf(var + EPSV) * gamma[f];
    float sh = beta[f] - mu * sc;
    int g = batch[r0];
    float s = 0.f, c = 0.f;
    for (int r = r0; r < r1; r++) {
        int gr = batch[r];
        if (gr != g) {
            atomicAdd(&pool[g * 128 + f], s);
            if (f == 0) atomicAdd(&cntf[g], c);
            s = 0.f; c = 0.f; g = gr;
        }
        unsigned int u = hb[(size_t)r * 64 + (f >> 1)];
        float2 vv = b2f2(u);
        float hv = (f & 1) ? vv.y : vv.x;
        s += elu1(hv * sc + sh);
        c += 1.f;
    }
    atomicAdd(&pool[g * 128 + f], s);
    if (f == 0) atomicAdd(&cntf[g], c);
}

__global__ void k_pool_fin(const float* __restrict__ pool, const float* __restrict__ cntf,
                           const float* __restrict__ Wc, const float* __restrict__ bc,
                           float* __restrict__ outp) {
    __shared__ float pr[128];
    int g = blockIdx.x, f = threadIdx.x;
    float c = fmaxf(cntf[g], 1.f);
    float pv = pool[g * 128 + f] / c;
    outp[g * 128 + f] = pv;
    pr[f] = pv;
    __syncthreads();
    if (f < CC) {
        float s = bc[f];
        for (int k = 0; k < 128; k++) s += pr[k] * Wc[k * CC + f];
        outp[GG * HH + g * CC + f] = s;
    }
}

// ---------------- launch ----------------

extern "C" void kernel_launch(void* const* d_in, const int* in_sizes, int n_in,
                              void* d_out, int out_size, void* d_ws, size_t ws_size,
                              hipStream_t stream) {
    const float* x = (const float*)d_in[0];
    const int* ei = (const int*)d_in[1];
    const int* batch = (const int*)d_in[2];
    const float* W1 = (const float*)d_in[3];
    const float* b1 = (const float*)d_in[4];
    const float* gamma1 = (const float*)d_in[5];
    const float* beta1 = (const float*)d_in[6];
    const float* Wl = (const float*)d_in[7];
    const float* bl = (const float*)d_in[8];
    const float* Wr = (const float*)d_in[9];
    const float* gamma2 = (const float*)d_in[10];
    const float* beta2 = (const float*)d_in[11];
    const float* W3 = (const float*)d_in[12];
    const float* att_src = (const float*)d_in[13];
    const float* att_dst = (const float*)d_in[14];
    const float* b3 = (const float*)d_in[15];
    const float* gamma3 = (const float*)d_in[16];
    const float* beta3 = (const float*)d_in[17];
    const float* Wc = (const float*)d_in[18];
    const float* bc = (const float*)d_in[19];

    char* w = (char*)d_ws;
    size_t o = 0;
    float* bufC = (float*)(w + o); o += (size_t)NN * 128 * 4;              // fp32 gemm2 out
    unsigned int* h0b = (unsigned int*)(w + o); o += (size_t)NN * 128 * 2;
    unsigned int* h1pre = (unsigned int*)(w + o); o += (size_t)NN * 128 * 2;
    unsigned int* h1b = (unsigned int*)(w + o); o += (size_t)NN * 128 * 2;
    unsigned int* sageb = (unsigned int*)(w + o); o += (size_t)NN * 128 * 2;
    unsigned int* h2f8 = (unsigned int*)(w + o); o += (size_t)NN * 128;    // fp8 e4m3
    unsigned int* aggDb = (unsigned int*)(w + o); o += (size_t)NN * 384 * 2;
    unsigned int* h3b = (unsigned int*)(w + o); o += (size_t)NN * 128 * 2;
    int* csr = (int*)(w + o); o += (size_t)EE * 4;
    int* deg = (int*)(w + o); o += (size_t)NN * 4;
    int* row_start = (int*)(w + o); o += (size_t)NN * 4;
    int* cursor = (int*)(w + o); o += (size_t)NN * 4;
    float* dinv = (float*)(w + o); o += (size_t)NN * 4;
    float* inv_sage = (float*)(w + o); o += (size_t)NN * 4;
    float4* asrc4 = (float4*)(w + o); o += (size_t)NN * 16;
    float4* adst4 = (float4*)(w + o); o += (size_t)NN * 16;
    float* bn1 = (float*)(w + o); o += 256 * 4;
    float* bn_sums23 = (float*)(w + o); o += 512 * 4;
    int* blk = (int*)(w + o); o += 1024;
    float* poolacc = (float*)(w + o); o += (size_t)GG * 128 * 4;
    float* cntf = (float*)(w + o); o += (size_t)GG * 4;
    float* wsrc = (float*)(w + o); o += 384 * 4;
    float* wdst = (float*)(w + o); o += 384 * 4;
    float4* alphaE = (float4*)(w + o); o += (size_t)EE * 16;
    short* w1hi = (short*)(w + o); o += (size_t)128 * 128 * 2;
    short* w1lo = (short*)(w + o); o += (size_t)128 * 128 * 2;
    short* wshi = (short*)(w + o); o += (size_t)256 * 128 * 2;
    short* wslo = (short*)(w + o); o += (size_t)256 * 128 * 2;
    short* w3hi = (short*)(w + o); o += (size_t)384 * 128 * 2;
    short* w3lo = (short*)(w + o); o += (size_t)384 * 128 * 2;

    float* outp = (float*)d_out;

    const int NB_SCAN = (NN + 255) / 256;
    const int EB = (EE + 255) / 256;
    const int NG8 = (NN + 7) / 8;     // gat: 2 nodes/wave
    const int NG16 = (NN + 15) / 16;  // gcn/sage: 4 nodes/wave
    const int GB64 = (NN + 63) / 64;  // gemm: BM=64 -> 782 blocks

    k_zero<<<NB_SCAN, 256, 0, stream>>>(deg, bn1, bn_sums23, poolacc);
    k_count_deg<<<EB, 256, 0, stream>>>(ei, deg);
    k_scan1<<<NB_SCAN, 256, 0, stream>>>(deg, row_start, blk);
    k_scan2<<<1, 256, 0, stream>>>(blk, NB_SCAN);
    k_scan3<<<NB_SCAN, 256, 0, stream>>>(row_start, blk, deg, cursor, dinv, inv_sage);
    k_fill<<<EB, 256, 0, stream>>>(ei, cursor, csr);
    k_prep_all<<<385, 256, 0, stream>>>(W1, Wl, Wr, W3, att_src, att_dst, w1hi, w1lo,
                                        wshi, wslo, w3hi, w3lo, wsrc, wdst);

    // Layer 1: GCN
    k_gemm_mfma<false, true, false><<<GB64, 256, 0, stream>>>(x, nullptr, w1hi, w1lo, nullptr,
                                                              h0b, nullptr, NN, 2, 2, 128);
    k_gcn_agg<<<NG16, 256, 0, stream>>>(h0b, row_start, deg, csr, dinv, b1, h1pre);
    k_bn_stats_b<<<1024, 128, 0, stream>>>(h1pre, bn1);
    k_bn_elu_b<<<NN * 32 / 256, 256, 0, stream>>>(h1pre, bn1, gamma1, beta1, h1b);

    // Layer 2: SAGE (fused K=256: [sage_agg | h1] @ [Wl; Wr] + bl, stats in epilogue)
    k_sage_agg<<<NG16, 256, 0, stream>>>(h1b, row_start, deg, csr, inv_sage, sageb);
    k_gemm_mfma<true, false, true><<<GB64, 256, 0, stream>>>(sageb, h1b, wshi, wslo, bl, bufC,
                                                             bn_sums23, NN, 2, 4, 128);
    k_bn_elu_att<<<NN * 32 / 256, 256, 0, stream>>>(bufC, bn_sums23, gamma2, beta2,
                                                    wsrc, wdst, h2f8, asrc4, adst4);

    // Layer 3: GAT (fp8 gathers, 2 nodes/wave; gemm3 writes bf16 + stats)
    k_gat_fused<<<NG8, 256, 0, stream>>>(h2f8, row_start, deg, csr, asrc4, adst4, alphaE, aggDb);
    k_gemm_mfma<true, true, true><<<GB64, 256, 0, stream>>>(aggDb, nullptr, w3hi, w3lo, b3, h3b,
                                                            bn_sums23 + 256, NN, 6, 6, 384);

    // Pool (BN+ELU inline, bf16 input) + classifier
    k_pool_bn<<<POOL_BLOCKS, 128, 0, stream>>>(h3b, batch, bn_sums23 + 256, gamma3, beta3,
                                               poolacc, cntf);
    k_pool_fin<<<GG, 128, 0, stream>>>(poolacc, cntf, Wc, bc, outp);
}

// Round 15
// 415.795 us; speedup vs baseline: 1.0252x; 1.0252x over previous
//
#include <hip/hip_runtime.h>
#include <math.h>

#define NN 50000
#define EE 500000
#define HH 128
#define NHEADS 3
#define CC 10
#define GG 64
#define EPSV 1e-5f
#define SLOPE 0.2f

typedef __attribute__((ext_vector_type(8))) short short8;
typedef __attribute__((ext_vector_type(4))) float f32x4;
typedef __attribute__((ext_vector_type(2))) float f32x2;

// ---------------- bf16 helpers (RNE) ----------------

__device__ __forceinline__ unsigned short f2b(float x) {
    unsigned int u = __builtin_bit_cast(unsigned int, x);
    return (unsigned short)((u + 0x7fffu + ((u >> 16) & 1u)) >> 16);
}
__device__ __forceinline__ unsigned int pack2(float a, float b) {
    return (unsigned int)f2b(a) | ((unsigned int)f2b(b) << 16);
}
__device__ __forceinline__ float2 b2f2(unsigned int u) {
    float2 r;
    r.x = __builtin_bit_cast(float, u << 16);
    r.y = __builtin_bit_cast(float, u & 0xffff0000u);
    return r;
}

// ---------------- fused zero-init ----------------

__global__ void k_zero(int* __restrict__ deg, float* __restrict__ bn1,
                       float* __restrict__ bn_sums23, float* __restrict__ poolacc) {
    int i = blockIdx.x * 256 + threadIdx.x;
    if (i < NN) deg[i] = 0;
    if (i < 256) bn1[i] = 0.f;
    if (i < 512) bn_sums23[i] = 0.f;
    if (i < GG * 128 + GG) poolacc[i] = 0.f;
}

// ---------------- CSR build ----------------

__global__ void k_count_deg(const int* __restrict__ ei, int* __restrict__ deg) {
    int e = blockIdx.x * 256 + threadIdx.x;
    if (e < EE) atomicAdd(&deg[ei[EE + e]], 1);
}

__global__ void k_scan1(const int* __restrict__ deg, int* __restrict__ row_start,
                        int* __restrict__ blk) {
    __shared__ int s[256];
    int i = blockIdx.x * 256 + threadIdx.x;
    int v = (i < NN) ? deg[i] : 0;
    s[threadIdx.x] = v;
    __syncthreads();
    for (int o = 1; o < 256; o <<= 1) {
        int t = (threadIdx.x >= o) ? s[threadIdx.x - o] : 0;
        __syncthreads();
        s[threadIdx.x] += t;
        __syncthreads();
    }
    if (i < NN) row_start[i] = s[threadIdx.x] - v;
    if (threadIdx.x == 255) blk[blockIdx.x] = s[255];
}

__global__ void k_scan2(int* __restrict__ blk, int nb) {
    __shared__ int s[256];
    int v = (threadIdx.x < nb) ? blk[threadIdx.x] : 0;
    s[threadIdx.x] = v;
    __syncthreads();
    for (int o = 1; o < 256; o <<= 1) {
        int t = (threadIdx.x >= o) ? s[threadIdx.x - o] : 0;
        __syncthreads();
        s[threadIdx.x] += t;
        __syncthreads();
    }
    if (threadIdx.x < nb) blk[threadIdx.x] = s[threadIdx.x] - v;
}

__global__ void k_scan3(int* __restrict__ row_start, const int* __restrict__ blk,
                        const int* __restrict__ deg, int* __restrict__ cursor,
                        float* __restrict__ dinv, float* __restrict__ inv_sage) {
    int i = blockIdx.x * 256 + threadIdx.x;
    if (i < NN) {
        int rs = row_start[i] + blk[blockIdx.x];
        row_start[i] = rs;
        cursor[i] = rs;
        int d = deg[i];
        dinv[i] = rsqrtf((float)(d + 1));
        inv_sage[i] = 1.0f / (float)(d > 1 ? d : 1);
    }
}

__global__ void k_fill(const int* __restrict__ ei, int* __restrict__ cursor,
                       int* __restrict__ csr_src) {
    int e = blockIdx.x * 256 + threadIdx.x;
    if (e < EE) {
        int d = ei[EE + e];
        int p = atomicAdd(&cursor[d], 1);
        csr_src[p] = ei[e];
    }
}

// ---------------- fused weight prep ----------------

__device__ __forceinline__ void split_store(float x, size_t dst, short* hi, short* lo) {
    unsigned int ux = __builtin_bit_cast(unsigned int, x);
    unsigned short hx = (unsigned short)(ux >> 16);
    float fx = __builtin_bit_cast(float, ux & 0xffff0000u);
    unsigned short lx = (unsigned short)(__builtin_bit_cast(unsigned int, x - fx) >> 16);
    hi[dst] = (short)hx;
    lo[dst] = (short)lx;
}

__device__ __forceinline__ void prep_one(float x, int k, int n, int cBase,
                                         short* hi, short* lo) {
    int c = (k >> 6) + cBase;
    int s = (k >> 5) & 1, quad = (k >> 3) & 3, j = k & 7;
    int G = n >> 4, l = quad * 16 + (n & 15);
    size_t dst = ((((size_t)(c * 2 + s)) * 8 + G) * 64 + l) * 8 + j;
    split_store(x, dst, hi, lo);
}

__global__ void k_prep_all(const float* __restrict__ W1, const float* __restrict__ Wl,
                           const float* __restrict__ Wr, const float* __restrict__ W3,
                           const float* __restrict__ att_src, const float* __restrict__ att_dst,
                           short* __restrict__ w1hi, short* __restrict__ w1lo,
                           short* __restrict__ wshi, short* __restrict__ wslo,
                           short* __restrict__ w3hi, short* __restrict__ w3lo,
                           float* __restrict__ wsrc, float* __restrict__ wdst) {
    int b = blockIdx.x, tid = threadIdx.x;
    if (b < 64) {
        int i = b * 256 + tid;
        prep_one(W1[i], i >> 7, i & 127, 0, w1hi, w1lo);
    } else if (b < 128) {
        int i = (b - 64) * 256 + tid;
        prep_one(Wl[i], i >> 7, i & 127, 0, wshi, wslo);
    } else if (b < 192) {
        int i = (b - 128) * 256 + tid;
        prep_one(Wr[i], i >> 7, i & 127, 2, wshi, wslo);
    } else if (b < 384) {
        int i = (b - 192) * 256 + tid;
        int k = i >> 7, n = i & 127;
        int h = k >> 7, kk = k & 127;
        float x = W3[(size_t)kk * 384 + h * 128 + n] * (1.f / 3.f);
        prep_one(x, k, n, 0, w3hi, w3lo);
    } else {
        for (int e = tid; e < 384; e += 256) {
            int h = e >> 7, k = e & 127;
            float s1 = 0.f, s2 = 0.f;
            const float* wrow = W3 + (size_t)k * 384 + h * 128;
            const float* as = att_src + h * 128;
            const float* ad = att_dst + h * 128;
            for (int j = 0; j < 128; j++) {
                float wv = wrow[j];
                s1 += wv * as[j];
                s2 += wv * ad[j];
            }
            wsrc[e] = s1;
            wdst[e] = s2;
        }
    }
}

// ---------------- MFMA GEMM  C = [A1|A2] @ B + bias (BM=128, batched loads) ------

template <bool ABF16, bool OUTB, bool STATS>
__global__ __launch_bounds__(256) void k_gemm_mfma(
    const void* __restrict__ A1v, const void* __restrict__ A2v,
    const short* __restrict__ Bhi, const short* __restrict__ Blo,
    const float* __restrict__ bias, void* __restrict__ Cv,
    float* __restrict__ sums, int M, int kc1, int kcT, int strideA1) {
    __shared__ short Ahi[128 * 72];
    __shared__ short Alo[ABF16 ? 8 : 128 * 72];
    __shared__ float cs[256];
    int tid = threadIdx.x;
    int rBase = blockIdx.x * 128;
    int wv = tid >> 6, lane = tid & 63;
    int rowHalf = wv >> 1, colHalf = wv & 1;
    int quad = lane >> 4, l15 = lane & 15;

    f32x4 acc[4][4];
#pragma unroll
    for (int a = 0; a < 4; a++)
#pragma unroll
        for (int b = 0; b < 4; b++) acc[a][b] = (f32x4)(0.f);

    for (int c = 0; c < kcT; c++) {
        const void* Asrc;
        int kOff, strideA;
        if (c < kc1) { Asrc = A1v; kOff = c * 64; strideA = strideA1; }
        else { Asrc = A2v; kOff = (c - kc1) * 64; strideA = 128; }

        __syncthreads();
        if (ABF16) {
            const unsigned short* As = (const unsigned short*)Asrc;
#pragma unroll
            for (int q = 0; q < 4; q++) {
                int slot = q * 256 + tid;
                int r = slot >> 3, k8 = slot & 7;
                uint4 v = make_uint4(0, 0, 0, 0);
                int gr = rBase + r;
                if (gr < M) v = *(const uint4*)(As + (size_t)gr * strideA + kOff + k8 * 8);
                *(uint4*)(Ahi + r * 72 + k8 * 8) = v;
            }
        } else {
            const float* As = (const float*)Asrc;
#pragma unroll
            for (int q8 = 0; q8 < 8; q8++) {
                int slot = q8 * 256 + tid;
                int r = slot >> 4, k4 = slot & 15;
                float4 v = make_float4(0.f, 0.f, 0.f, 0.f);
                int gr = rBase + r;
                if (gr < M) v = *(const float4*)(As + (size_t)gr * strideA + kOff + k4 * 4);
                unsigned int ux = __builtin_bit_cast(unsigned int, v.x);
                unsigned int uy = __builtin_bit_cast(unsigned int, v.y);
                unsigned int uz = __builtin_bit_cast(unsigned int, v.z);
                unsigned int uw = __builtin_bit_cast(unsigned int, v.w);
                unsigned int hx = ux >> 16, hy = uy >> 16, hz = uz >> 16, hw = uw >> 16;
                float fx = __builtin_bit_cast(float, ux & 0xffff0000u);
                float fy = __builtin_bit_cast(float, uy & 0xffff0000u);
                float fz = __builtin_bit_cast(float, uz & 0xffff0000u);
                float fw = __builtin_bit_cast(float, uw & 0xffff0000u);
                unsigned int lx = __builtin_bit_cast(unsigned int, v.x - fx) >> 16;
                unsigned int ly = __builtin_bit_cast(unsigned int, v.y - fy) >> 16;
                unsigned int lz = __builtin_bit_cast(unsigned int, v.z - fz) >> 16;
                unsigned int lw = __builtin_bit_cast(unsigned int, v.w - fw) >> 16;
                uint2 ph = make_uint2(hx | (hy << 16), hz | (hw << 16));
                uint2 pl = make_uint2(lx | (ly << 16), lz | (lw << 16));
                *(uint2*)(Ahi + r * 72 + k4 * 4) = ph;
                *(uint2*)(Alo + r * 72 + k4 * 4) = pl;
            }
        }
        __syncthreads();

        // ---- batch ALL loads for this k-chunk before any MFMA ----
        short8 bh[2][4], bl[2][4];
#pragma unroll
        for (int s = 0; s < 2; s++) {
#pragma unroll
            for (int cg = 0; cg < 4; cg++) {
                int G = colHalf * 4 + cg;
                size_t bo = ((((size_t)(c * 2 + s)) * 8 + G) * 64 + lane) * 8;
                bh[s][cg] = *(const short8*)(Bhi + bo);
                bl[s][cg] = *(const short8*)(Blo + bo);
            }
        }
        short8 ah[2][4], al[2][4];
#pragma unroll
        for (int s = 0; s < 2; s++) {
#pragma unroll
            for (int rb = 0; rb < 4; rb++) {
                int m = rowHalf * 64 + rb * 16 + l15;
                ah[s][rb] = *(const short8*)(Ahi + m * 72 + s * 32 + quad * 8);
                if (!ABF16) al[s][rb] = *(const short8*)(Alo + m * 72 + s * 32 + quad * 8);
            }
        }

#pragma unroll
        for (int s = 0; s < 2; s++) {
#pragma unroll
            for (int cg = 0; cg < 4; cg++) {
#pragma unroll
                for (int rb = 0; rb < 4; rb++) {
                    acc[rb][cg] = __builtin_amdgcn_mfma_f32_16x16x32_bf16(ah[s][rb], bh[s][cg], acc[rb][cg], 0, 0, 0);
                    if (!ABF16)
                        acc[rb][cg] = __builtin_amdgcn_mfma_f32_16x16x32_bf16(al[s][rb], bh[s][cg], acc[rb][cg], 0, 0, 0);
                    acc[rb][cg] = __builtin_amdgcn_mfma_f32_16x16x32_bf16(ah[s][rb], bl[s][cg], acc[rb][cg], 0, 0, 0);
                }
            }
        }
    }

    if (STATS) {
        cs[tid] = 0.f;
        __syncthreads();
    }

#pragma unroll
    for (int cg = 0; cg < 4; cg++) {
        int col = colHalf * 64 + cg * 16 + l15;
        float bv = bias ? bias[col] : 0.f;
        float ps = 0.f, pq = 0.f;
#pragma unroll
        for (int rb = 0; rb < 4; rb++) {
#pragma unroll
            for (int r = 0; r < 4; r++) {
                int row = rBase + rowHalf * 64 + rb * 16 + quad * 4 + r;
                if (row < M) {
                    float ov = acc[rb][cg][r] + bv;
                    if (OUTB) ((unsigned short*)Cv)[(size_t)row * HH + col] = f2b(ov);
                    else ((float*)Cv)[(size_t)row * HH + col] = ov;
                    if (STATS) { ps += ov; pq += ov * ov; }
                }
            }
        }
        if (STATS) {
            ps += __shfl_xor(ps, 16, 64); ps += __shfl_xor(ps, 32, 64);
            pq += __shfl_xor(pq, 16, 64); pq += __shfl_xor(pq, 32, 64);
            if (quad == 0) {
                atomicAdd(&cs[col], ps);
                atomicAdd(&cs[128 + col], pq);
            }
        }
    }
    if (STATS) {
        __syncthreads();
        atomicAdd(&sums[tid], cs[tid]);
    }
}

// ---------------- GCN aggregation (4 nodes/wave, 16 lanes each, uint4 loads) -----

__global__ void k_gcn_agg(const unsigned int* __restrict__ hb, const int* __restrict__ row_start,
                          const int* __restrict__ deg, const int* __restrict__ csr,
                          const float* __restrict__ dinv, const float* __restrict__ b1,
                          unsigned int* __restrict__ outb) {
    int tid = threadIdx.x;
    int n = blockIdx.x * 16 + (tid >> 4);
    if (n >= NN) return;
    int l = tid & 15;
    const uint4* hb4 = (const uint4*)hb;
    float di = dinv[n];
    float wsq = di * di;
    uint4 hv4 = hb4[(size_t)n * 16 + l];
    float2 p0 = b2f2(hv4.x), p1 = b2f2(hv4.y), p2 = b2f2(hv4.z), p3 = b2f2(hv4.w);
    float acc[8] = {p0.x * wsq, p0.y * wsq, p1.x * wsq, p1.y * wsq,
                    p2.x * wsq, p2.y * wsq, p3.x * wsq, p3.y * wsq};
    int s0 = row_start[n], cnt = deg[n];
    int i = 0;
    for (; i + 4 <= cnt; i += 4) {
        int ss[4]; float ww[4]; uint4 vv[4];
#pragma unroll
        for (int j = 0; j < 4; j++) ss[j] = csr[s0 + i + j];
#pragma unroll
        for (int j = 0; j < 4; j++) { ww[j] = dinv[ss[j]]; vv[j] = hb4[(size_t)ss[j] * 16 + l]; }
#pragma unroll
        for (int j = 0; j < 4; j++) {
            float wj = ww[j] * di;
            float2 q0 = b2f2(vv[j].x), q1 = b2f2(vv[j].y), q2 = b2f2(vv[j].z), q3 = b2f2(vv[j].w);
            acc[0] += q0.x * wj; acc[1] += q0.y * wj;
            acc[2] += q1.x * wj; acc[3] += q1.y * wj;
            acc[4] += q2.x * wj; acc[5] += q2.y * wj;
            acc[6] += q3.x * wj; acc[7] += q3.y * wj;
        }
    }
    for (; i < cnt; i++) {
        int s = csr[s0 + i];
        float wj = dinv[s] * di;
        uint4 v = hb4[(size_t)s * 16 + l];
        float2 q0 = b2f2(v.x), q1 = b2f2(v.y), q2 = b2f2(v.z), q3 = b2f2(v.w);
        acc[0] += q0.x * wj; acc[1] += q0.y * wj;
        acc[2] += q1.x * wj; acc[3] += q1.y * wj;
        acc[4] += q2.x * wj; acc[5] += q2.y * wj;
        acc[6] += q3.x * wj; acc[7] += q3.y * wj;
    }
    float4 bb0 = *(const float4*)(b1 + l * 8);
    float4 bb1 = *(const float4*)(b1 + l * 8 + 4);
    uint4 o;
    o.x = pack2(acc[0] + bb0.x, acc[1] + bb0.y);
    o.y = pack2(acc[2] + bb0.z, acc[3] + bb0.w);
    o.z = pack2(acc[4] + bb1.x, acc[5] + bb1.y);
    o.w = pack2(acc[6] + bb1.z, acc[7] + bb1.w);
    ((uint4*)outb)[(size_t)n * 16 + l] = o;
}

// ---------------- BN stats over bf16 array (separate, cheap) ----------------

__global__ void k_bn_stats_b(const unsigned int* __restrict__ hb, float* __restrict__ sums) {
    int f = threadIdx.x;
    int rows_per = (NN + gridDim.x - 1) / gridDim.x;
    int r0 = blockIdx.x * rows_per;
    int r1 = r0 + rows_per;
    if (r1 > NN) r1 = NN;
    int wi = f >> 1, hi = f & 1;
    float s = 0.f, sq = 0.f;
    for (int r = r0; r < r1; r++) {
        float2 vv = b2f2(hb[(size_t)r * 64 + wi]);
        float v = hi ? vv.y : vv.x;
        s += v;
        sq += v * v;
    }
    atomicAdd(&sums[f], s);
    atomicAdd(&sums[128 + f], sq);
}

// ---------------- SAGE aggregation (4 nodes/wave, 16 lanes each, uint4 loads) ----

__global__ void k_sage_agg(const unsigned int* __restrict__ hb, const int* __restrict__ row_start,
                           const int* __restrict__ deg, const int* __restrict__ csr,
                           const float* __restrict__ inv_sage, unsigned int* __restrict__ outb) {
    int tid = threadIdx.x;
    int n = blockIdx.x * 16 + (tid >> 4);
    if (n >= NN) return;
    int l = tid & 15;
    const uint4* hb4 = (const uint4*)hb;
    float acc[8] = {0.f, 0.f, 0.f, 0.f, 0.f, 0.f, 0.f, 0.f};
    int s0 = row_start[n], cnt = deg[n];
    int i = 0;
    for (; i + 4 <= cnt; i += 4) {
        int ss[4]; uint4 vv[4];
#pragma unroll
        for (int j = 0; j < 4; j++) ss[j] = csr[s0 + i + j];
#pragma unroll
        for (int j = 0; j < 4; j++) vv[j] = hb4[(size_t)ss[j] * 16 + l];
#pragma unroll
        for (int j = 0; j < 4; j++) {
            float2 q0 = b2f2(vv[j].x), q1 = b2f2(vv[j].y), q2 = b2f2(vv[j].z), q3 = b2f2(vv[j].w);
            acc[0] += q0.x; acc[1] += q0.y;
            acc[2] += q1.x; acc[3] += q1.y;
            acc[4] += q2.x; acc[5] += q2.y;
            acc[6] += q3.x; acc[7] += q3.y;
        }
    }
    for (; i < cnt; i++) {
        uint4 v = hb4[(size_t)csr[s0 + i] * 16 + l];
        float2 q0 = b2f2(v.x), q1 = b2f2(v.y), q2 = b2f2(v.z), q3 = b2f2(v.w);
        acc[0] += q0.x; acc[1] += q0.y;
        acc[2] += q1.x; acc[3] += q1.y;
        acc[4] += q2.x; acc[5] += q2.y;
        acc[6] += q3.x; acc[7] += q3.y;
    }
    float sc = inv_sage[n];
    uint4 o;
    o.x = pack2(acc[0] * sc, acc[1] * sc);
    o.y = pack2(acc[2] * sc, acc[3] * sc);
    o.z = pack2(acc[4] * sc, acc[5] * sc);
    o.w = pack2(acc[6] * sc, acc[7] * sc);
    ((uint4*)outb)[(size_t)n * 16 + l] = o;
}

// ---------------- GAT: fused softmax + aggregation (2 nodes/wave, fp8, pk-fma) ---

__device__ __forceinline__ float lrelu(float a) { return fmaxf(a, SLOPE * a); }

__global__ void k_gat_fused(const unsigned int* __restrict__ h8u, const int* __restrict__ row_start,
                            const int* __restrict__ deg, const int* __restrict__ csr,
                            const float4* __restrict__ asrc4, const float4* __restrict__ adst4,
                            float4* __restrict__ alphaE, unsigned int* __restrict__ aggb) {
    int tid = threadIdx.x;
    int wv = tid >> 6, lane = tid & 63;
    int half = lane >> 5, l = lane & 31;
    int n = blockIdx.x * 8 + wv * 2 + half;
    if (n >= NN) return;
    float4 ad = adst4[n], asv = asrc4[n];
    float es0 = lrelu(asv.x + ad.x), es1 = lrelu(asv.y + ad.y), es2 = lrelu(asv.z + ad.z);
    int s0 = row_start[n], cnt = deg[n];
    float self0, self1, self2;
    unsigned int pk1 = 0, pk2 = 0;
    bool fast = (cnt <= 32);
    if (fast) {
        bool valid = l < cnt;
        int sReg = 0;
        float e0 = -3e38f, e1 = -3e38f, e2 = -3e38f;
        if (valid) {
            sReg = csr[s0 + l];
            float4 a4 = asrc4[sReg];
            e0 = lrelu(a4.x + ad.x); e1 = lrelu(a4.y + ad.y); e2 = lrelu(a4.z + ad.z);
        }
        float M0 = e0, M1 = e1, M2 = e2;
#pragma unroll
        for (int o = 16; o > 0; o >>= 1) {
            M0 = fmaxf(M0, __shfl_xor(M0, o, 64));
            M1 = fmaxf(M1, __shfl_xor(M1, o, 64));
            M2 = fmaxf(M2, __shfl_xor(M2, o, 64));
        }
        float m0 = fmaxf(es0, M0), m1 = fmaxf(es1, M1), m2 = fmaxf(es2, M2);
        float w0 = valid ? __expf(e0 - m0) : 0.f;
        float w1 = valid ? __expf(e1 - m1) : 0.f;
        float w2 = valid ? __expf(e2 - m2) : 0.f;
        float S0 = w0, S1 = w1, S2 = w2;
#pragma unroll
        for (int o = 16; o > 0; o >>= 1) {
            S0 += __shfl_xor(S0, o, 64);
            S1 += __shfl_xor(S1, o, 64);
            S2 += __shfl_xor(S2, o, 64);
        }
        float sw0 = __expf(es0 - m0), sw1 = __expf(es1 - m1), sw2 = __expf(es2 - m2);
        float r0 = 1.f / (S0 + sw0), r1 = 1.f / (S1 + sw1), r2 = 1.f / (S2 + sw2);
        pk1 = ((unsigned int)sReg & 0xffffu) | ((unsigned int)f2b(w2 * r2) << 16);
        pk2 = pack2(w0 * r0, w1 * r1);
        self0 = sw0 * r0; self1 = sw1 * r1; self2 = sw2 * r2;
    } else {
        float m0 = es0, m1 = es1, m2 = es2;
        for (int base = 0; base < cnt; base += 32) {
            int i2 = base + l;
            float e0 = -3e38f, e1 = -3e38f, e2 = -3e38f;
            if (i2 < cnt) {
                int s = csr[s0 + i2];
                float4 a4 = asrc4[s];
                e0 = lrelu(a4.x + ad.x); e1 = lrelu(a4.y + ad.y); e2 = lrelu(a4.z + ad.z);
                alphaE[s0 + i2] = make_float4(e0, e1, e2, 0.f);
            }
#pragma unroll
            for (int o = 16; o > 0; o >>= 1) {
                e0 = fmaxf(e0, __shfl_xor(e0, o, 64));
                e1 = fmaxf(e1, __shfl_xor(e1, o, 64));
                e2 = fmaxf(e2, __shfl_xor(e2, o, 64));
            }
            m0 = fmaxf(m0, e0); m1 = fmaxf(m1, e1); m2 = fmaxf(m2, e2);
        }
        float l0 = __expf(es0 - m0), l1 = __expf(es1 - m1), l2 = __expf(es2 - m2);
        for (int base = 0; base < cnt; base += 32) {
            int i2 = base + l;
            float w0 = 0.f, w1 = 0.f, w2 = 0.f;
            if (i2 < cnt) {
                float4 e = alphaE[s0 + i2];
                w0 = __expf(e.x - m0); w1 = __expf(e.y - m1); w2 = __expf(e.z - m2);
            }
#pragma unroll
            for (int o = 16; o > 0; o >>= 1) {
                w0 += __shfl_xor(w0, o, 64);
                w1 += __shfl_xor(w1, o, 64);
                w2 += __shfl_xor(w2, o, 64);
            }
            l0 += w0; l1 += w1; l2 += w2;
        }
        float r0 = 1.f / l0, r1 = 1.f / l1, r2 = 1.f / l2;
        self0 = __expf(es0 - m0) * r0;
        self1 = __expf(es1 - m1) * r1;
        self2 = __expf(es2 - m2) * r2;
        for (int base = 0; base < cnt; base += 32) {
            int i2 = base + l;
            if (i2 < cnt) {
                float4 e = alphaE[s0 + i2];
                alphaE[s0 + i2] = make_float4(__expf(e.x - m0) * r0, __expf(e.y - m1) * r1,
                                              __expf(e.z - m2) * r2, 0.f);
            }
        }
    }

    unsigned int hvu = h8u[(size_t)n * 32 + l];
    f32x2 v01 = __builtin_amdgcn_cvt_pk_f32_fp8((int)hvu, false);
    f32x2 v23 = __builtin_amdgcn_cvt_pk_f32_fp8((int)hvu, true);
    f32x2 a0l = v01 * self0, a0h = v23 * self0;
    f32x2 a1l = v01 * self1, a1h = v23 * self1;
    f32x2 a2l = v01 * self2, a2h = v23 * self2;
    int lbase = half << 5;
    if (fast) {
        int i = 0;
        for (; i + 4 <= cnt; i += 4) {
            unsigned int q1[4], q2[4], uu[4];
#pragma unroll
            for (int j = 0; j < 4; j++) {
                q1[j] = __shfl(pk1, lbase + i + j, 64);
                q2[j] = __shfl(pk2, lbase + i + j, 64);
            }
#pragma unroll
            for (int j = 0; j < 4; j++) uu[j] = h8u[(size_t)(q1[j] & 0xffffu) * 32 + l];
#pragma unroll
            for (int j = 0; j < 4; j++) {
                f32x2 w01 = __builtin_amdgcn_cvt_pk_f32_fp8((int)uu[j], false);
                f32x2 w23 = __builtin_amdgcn_cvt_pk_f32_fp8((int)uu[j], true);
                float2 a01 = b2f2(q2[j]);
                float w2 = __builtin_bit_cast(float, q1[j] & 0xffff0000u);
                a0l += a01.x * w01; a0h += a01.x * w23;
                a1l += a01.y * w01; a1h += a01.y * w23;
                a2l += w2 * w01;    a2h += w2 * w23;
            }
        }
        for (; i < cnt; i++) {
            unsigned int q1 = __shfl(pk1, lbase + i, 64);
            unsigned int q2 = __shfl(pk2, lbase + i, 64);
            unsigned int u = h8u[(size_t)(q1 & 0xffffu) * 32 + l];
            f32x2 w01 = __builtin_amdgcn_cvt_pk_f32_fp8((int)u, false);
            f32x2 w23 = __builtin_amdgcn_cvt_pk_f32_fp8((int)u, true);
            float2 a01 = b2f2(q2);
            float w2 = __builtin_bit_cast(float, q1 & 0xffff0000u);
            a0l += a01.x * w01; a0h += a01.x * w23;
            a1l += a01.y * w01; a1h += a01.y * w23;
            a2l += w2 * w01;    a2h += w2 * w23;
        }
    } else {
        for (int i = 0; i < cnt; i++) {
            int s = csr[s0 + i];
            float4 al = alphaE[s0 + i];
            unsigned int u = h8u[(size_t)s * 32 + l];
            f32x2 w01 = __builtin_amdgcn_cvt_pk_f32_fp8((int)u, false);
            f32x2 w23 = __builtin_amdgcn_cvt_pk_f32_fp8((int)u, true);
            a0l += al.x * w01; a0h += al.x * w23;
            a1l += al.y * w01; a1h += al.y * w23;
            a2l += al.z * w01; a2h += al.z * w23;
        }
    }
    unsigned int* op = aggb + (size_t)n * 192 + 2 * l;
    *(uint2*)(op) = make_uint2(pack2(a0l.x, a0l.y), pack2(a0h.x, a0h.y));
    *(uint2*)(op + 64) = make_uint2(pack2(a1l.x, a1l.y), pack2(a1h.x, a1h.y));
    *(uint2*)(op + 128) = make_uint2(pack2(a2l.x, a2l.y), pack2(a2h.x, a2h.y));
}

// ---------------- BatchNorm + ELU ----------------

__device__ __forceinline__ float elu1(float x) { return x > 0.f ? x : (__expf(x) - 1.f); }

__device__ __forceinline__ float4 bn_apply4(float4 v, const float* sums,
                                            const float* gamma, const float* beta, int f4) {
    const float invN = 1.0f / NN;
    float4 s4 = *(const float4*)(sums + f4);
    float4 q4 = *(const float4*)(sums + 128 + f4);
    float4 g4 = *(const float4*)(gamma + f4);
    float4 b4 = *(const float4*)(beta + f4);
    float mx = s4.x * invN, my = s4.y * invN, mz = s4.z * invN, mw = s4.w * invN;
    float scx = rsqrtf(q4.x * invN - mx * mx + EPSV) * g4.x;
    float scy = rsqrtf(q4.y * invN - my * my + EPSV) * g4.y;
    float scz = rsqrtf(q4.z * invN - mz * mz + EPSV) * g4.z;
    float scw = rsqrtf(q4.w * invN - mw * mw + EPSV) * g4.w;
    v.x = elu1(v.x * scx + (b4.x - mx * scx));
    v.y = elu1(v.y * scy + (b4.y - my * scy));
    v.z = elu1(v.z * scz + (b4.z - mz * scz));
    v.w = elu1(v.w * scw + (b4.w - mw * scw));
    return v;
}

__global__ void k_bn_elu_b(const unsigned int* __restrict__ hpre, const float* __restrict__ sums,
                           const float* __restrict__ gamma, const float* __restrict__ beta,
                           unsigned int* __restrict__ hb) {
    int i = blockIdx.x * 256 + threadIdx.x;
    int f4 = (i & 31) << 2;
    uint2 p = *(const uint2*)(hpre + (size_t)(i >> 5) * 64 + (i & 31) * 2);
    float2 v01 = b2f2(p.x), v23 = b2f2(p.y);
    float4 v = make_float4(v01.x, v01.y, v23.x, v23.y);
    v = bn_apply4(v, sums, gamma, beta, f4);
    uint2 q = make_uint2(pack2(v.x, v.y), pack2(v.z, v.w));
    *(uint2*)(hb + (size_t)(i >> 5) * 64 + (i & 31) * 2) = q;
}

__global__ void k_bn_elu_att(const float* __restrict__ h, const float* __restrict__ sums,
                             const float* __restrict__ gamma, const float* __restrict__ beta,
                             const float* __restrict__ wsrc, const float* __restrict__ wdst,
                             unsigned int* __restrict__ h8w, float4* __restrict__ asrc4,
                             float4* __restrict__ adst4) {
    int i = blockIdx.x * 256 + threadIdx.x;
    int fi = i & 31;
    int f4 = fi << 2;
    float4 v = bn_apply4(((const float4*)h)[i], sums, gamma, beta, f4);
    int p8 = __builtin_amdgcn_cvt_pk_fp8_f32(v.x, v.y, 0, false);
    p8 = __builtin_amdgcn_cvt_pk_fp8_f32(v.z, v.w, p8, true);
    h8w[(size_t)(i >> 5) * 32 + fi] = (unsigned int)p8;
    const float4* ws4 = (const float4*)wsrc;
    const float4* wd4 = (const float4*)wdst;
    float d[6];
#pragma unroll
    for (int hd = 0; hd < 3; hd++) {
        float4 a = ws4[hd * 32 + fi];
        float4 b = wd4[hd * 32 + fi];
        d[hd] = v.x * a.x + v.y * a.y + v.z * a.z + v.w * a.w;
        d[3 + hd] = v.x * b.x + v.y * b.y + v.z * b.z + v.w * b.w;
    }
#pragma unroll
    for (int o = 16; o > 0; o >>= 1) {
#pragma unroll
        for (int j = 0; j < 6; j++) d[j] += __shfl_xor(d[j], o, 64);
    }
    if ((threadIdx.x & 31) == 0) {
        int r = i >> 5;
        asrc4[r] = make_float4(d[0], d[1], d[2], 0.f);
        adst4[r] = make_float4(d[3], d[4], d[5], 0.f);
    }
}

// ---------------- Pool (BN+ELU fused, bf16 input) + classifier ----------------

#define POOL_BLOCKS 800

__global__ void k_pool_bn(const unsigned int* __restrict__ hb, const int* __restrict__ batch,
                          const float* __restrict__ sums, const float* __restrict__ gamma,
                          const float* __restrict__ beta, float* __restrict__ pool,
                          float* __restrict__ cntf) {
    const int RP = (NN + POOL_BLOCKS - 1) / POOL_BLOCKS;
    int r0 = blockIdx.x * RP;
    int r1 = r0 + RP;
    if (r1 > NN) r1 = NN;
    if (r0 >= r1) return;
    int f = threadIdx.x;
    const float invN = 1.0f / NN;
    float mu = sums[f] * invN;
    float var = sums[128 + f] * invN - mu * mu;
    float sc = rsqrtf(var + EPSV) * gamma[f];
    float sh = beta[f] - mu * sc;
    int g = batch[r0];
    float s = 0.f, c = 0.f;
    for (int r = r0; r < r1; r++) {
        int gr = batch[r];
        if (gr != g) {
            atomicAdd(&pool[g * 128 + f], s);
            if (f == 0) atomicAdd(&cntf[g], c);
            s = 0.f; c = 0.f; g = gr;
        }
        unsigned int u = hb[(size_t)r * 64 + (f >> 1)];
        float2 vv = b2f2(u);
        float hv = (f & 1) ? vv.y : vv.x;
        s += elu1(hv * sc + sh);
        c += 1.f;
    }
    atomicAdd(&pool[g * 128 + f], s);
    if (f == 0) atomicAdd(&cntf[g], c);
}

__global__ void k_pool_fin(const float* __restrict__ pool, const float* __restrict__ cntf,
                           const float* __restrict__ Wc, const float* __restrict__ bc,
                           float* __restrict__ outp) {
    __shared__ float pr[128];
    int g = blockIdx.x, f = threadIdx.x;
    float c = fmaxf(cntf[g], 1.f);
    float pv = pool[g * 128 + f] / c;
    outp[g * 128 + f] = pv;
    pr[f] = pv;
    __syncthreads();
    if (f < CC) {
        float s = bc[f];
        for (int k = 0; k < 128; k++) s += pr[k] * Wc[k * CC + f];
        outp[GG * HH + g * CC + f] = s;
    }
}

// ---------------- launch ----------------

extern "C" void kernel_launch(void* const* d_in, const int* in_sizes, int n_in,
                              void* d_out, int out_size, void* d_ws, size_t ws_size,
                              hipStream_t stream) {
    const float* x = (const float*)d_in[0];
    const int* ei = (const int*)d_in[1];
    const int* batch = (const int*)d_in[2];
    const float* W1 = (const float*)d_in[3];
    const float* b1 = (const float*)d_in[4];
    const float* gamma1 = (const float*)d_in[5];
    const float* beta1 = (const float*)d_in[6];
    const float* Wl = (const float*)d_in[7];
    const float* bl = (const float*)d_in[8];
    const float* Wr = (const float*)d_in[9];
    const float* gamma2 = (const float*)d_in[10];
    const float* beta2 = (const float*)d_in[11];
    const float* W3 = (const float*)d_in[12];
    const float* att_src = (const float*)d_in[13];
    const float* att_dst = (const float*)d_in[14];
    const float* b3 = (const float*)d_in[15];
    const float* gamma3 = (const float*)d_in[16];
    const float* beta3 = (const float*)d_in[17];
    const float* Wc = (const float*)d_in[18];
    const float* bc = (const float*)d_in[19];

    char* w = (char*)d_ws;
    size_t o = 0;
    float* bufC = (float*)(w + o); o += (size_t)NN * 128 * 4;
    unsigned int* h0b = (unsigned int*)(w + o); o += (size_t)NN * 128 * 2;
    unsigned int* h1pre = (unsigned int*)(w + o); o += (size_t)NN * 128 * 2;
    unsigned int* h1b = (unsigned int*)(w + o); o += (size_t)NN * 128 * 2;
    unsigned int* sageb = (unsigned int*)(w + o); o += (size_t)NN * 128 * 2;
    unsigned int* h2f8 = (unsigned int*)(w + o); o += (size_t)NN * 128;
    unsigned int* aggDb = (unsigned int*)(w + o); o += (size_t)NN * 384 * 2;
    unsigned int* h3b = (unsigned int*)(w + o); o += (size_t)NN * 128 * 2;
    int* csr = (int*)(w + o); o += (size_t)EE * 4;
    int* deg = (int*)(w + o); o += (size_t)NN * 4;
    int* row_start = (int*)(w + o); o += (size_t)NN * 4;
    int* cursor = (int*)(w + o); o += (size_t)NN * 4;
    float* dinv = (float*)(w + o); o += (size_t)NN * 4;
    float* inv_sage = (float*)(w + o); o += (size_t)NN * 4;
    float4* asrc4 = (float4*)(w + o); o += (size_t)NN * 16;
    float4* adst4 = (float4*)(w + o); o += (size_t)NN * 16;
    float* bn1 = (float*)(w + o); o += 256 * 4;
    float* bn_sums23 = (float*)(w + o); o += 512 * 4;
    int* blk = (int*)(w + o); o += 1024;
    float* poolacc = (float*)(w + o); o += (size_t)GG * 128 * 4;
    float* cntf = (float*)(w + o); o += (size_t)GG * 4;
    float* wsrc = (float*)(w + o); o += 384 * 4;
    float* wdst = (float*)(w + o); o += 384 * 4;
    float4* alphaE = (float4*)(w + o); o += (size_t)EE * 16;
    short* w1hi = (short*)(w + o); o += (size_t)128 * 128 * 2;
    short* w1lo = (short*)(w + o); o += (size_t)128 * 128 * 2;
    short* wshi = (short*)(w + o); o += (size_t)256 * 128 * 2;
    short* wslo = (short*)(w + o); o += (size_t)256 * 128 * 2;
    short* w3hi = (short*)(w + o); o += (size_t)384 * 128 * 2;
    short* w3lo = (short*)(w + o); o += (size_t)384 * 128 * 2;

    float* outp = (float*)d_out;

    const int NB_SCAN = (NN + 255) / 256;
    const int EB = (EE + 255) / 256;
    const int NG8 = (NN + 7) / 8;
    const int NG16 = (NN + 15) / 16;
    const int GB = (NN + 127) / 128;  // BM=128 -> 391 blocks

    k_zero<<<NB_SCAN, 256, 0, stream>>>(deg, bn1, bn_sums23, poolacc);
    k_count_deg<<<EB, 256, 0, stream>>>(ei, deg);
    k_scan1<<<NB_SCAN, 256, 0, stream>>>(deg, row_start, blk);
    k_scan2<<<1, 256, 0, stream>>>(blk, NB_SCAN);
    k_scan3<<<NB_SCAN, 256, 0, stream>>>(row_start, blk, deg, cursor, dinv, inv_sage);
    k_fill<<<EB, 256, 0, stream>>>(ei, cursor, csr);
    k_prep_all<<<385, 256, 0, stream>>>(W1, Wl, Wr, W3, att_src, att_dst, w1hi, w1lo,
                                        wshi, wslo, w3hi, w3lo, wsrc, wdst);

    // Layer 1: GCN
    k_gemm_mfma<false, true, false><<<GB, 256, 0, stream>>>(x, nullptr, w1hi, w1lo, nullptr,
                                                            h0b, nullptr, NN, 2, 2, 128);
    k_gcn_agg<<<NG16, 256, 0, stream>>>(h0b, row_start, deg, csr, dinv, b1, h1pre);
    k_bn_stats_b<<<1024, 128, 0, stream>>>(h1pre, bn1);
    k_bn_elu_b<<<NN * 32 / 256, 256, 0, stream>>>(h1pre, bn1, gamma1, beta1, h1b);

    // Layer 2: SAGE
    k_sage_agg<<<NG16, 256, 0, stream>>>(h1b, row_start, deg, csr, inv_sage, sageb);
    k_gemm_mfma<true, false, true><<<GB, 256, 0, stream>>>(sageb, h1b, wshi, wslo, bl, bufC,
                                                           bn_sums23, NN, 2, 4, 128);
    k_bn_elu_att<<<NN * 32 / 256, 256, 0, stream>>>(bufC, bn_sums23, gamma2, beta2,
                                                    wsrc, wdst, h2f8, asrc4, adst4);

    // Layer 3: GAT
    k_gat_fused<<<NG8, 256, 0, stream>>>(h2f8, row_start, deg, csr, asrc4, adst4, alphaE, aggDb);
    k_gemm_mfma<true, true, true><<<GB, 256, 0, stream>>>(aggDb, nullptr, w3hi, w3lo, b3, h3b,
                                                          bn_sums23 + 256, NN, 6, 6, 384);

    // Pool + classifier
    k_pool_bn<<<POOL_BLOCKS, 128, 0, stream>>>(h3b, batch, bn_sums23 + 256, gamma3, beta3,
                                               poolacc, cntf);
    k_pool_fin<<<GG, 128, 0, stream>>>(poolacc, cntf, Wc, bc, outp);
}

// Round 16
// 415.409 us; speedup vs baseline: 1.0262x; 1.0009x over previous
//
#include <hip/hip_runtime.h>
#include <math.h>

#define NN 50000
#define EE 500000
#define HH 128
#define NHEADS 3
#define CC 10
#define GG 64
#define EPSV 1e-5f
#define SLOPE 0.2f

typedef __attribute__((ext_vector_type(8))) short short8;
typedef __attribute__((ext_vector_type(4))) float f32x4;
typedef __attribute__((ext_vector_type(2))) float f32x2;

// ---------------- bf16 helpers (RNE) ----------------

__device__ __forceinline__ unsigned short f2b(float x) {
    unsigned int u = __builtin_bit_cast(unsigned int, x);
    return (unsigned short)((u + 0x7fffu + ((u >> 16) & 1u)) >> 16);
}
__device__ __forceinline__ unsigned int pack2(float a, float b) {
    return (unsigned int)f2b(a) | ((unsigned int)f2b(b) << 16);
}
__device__ __forceinline__ float2 b2f2(unsigned int u) {
    float2 r;
    r.x = __builtin_bit_cast(float, u << 16);
    r.y = __builtin_bit_cast(float, u & 0xffff0000u);
    return r;
}

// ---------------- fused zero-init ----------------

__global__ void k_zero(int* __restrict__ deg, float* __restrict__ bn1,
                       float* __restrict__ bn_sums23, float* __restrict__ poolacc) {
    int i = blockIdx.x * 256 + threadIdx.x;
    if (i < NN) deg[i] = 0;
    if (i < 256) bn1[i] = 0.f;
    if (i < 512) bn_sums23[i] = 0.f;
    if (i < GG * 128 + GG) poolacc[i] = 0.f;
}

// ---------------- CSR build ----------------

__global__ void k_count_deg(const int* __restrict__ ei, int* __restrict__ deg) {
    int e = blockIdx.x * 256 + threadIdx.x;
    if (e < EE) atomicAdd(&deg[ei[EE + e]], 1);
}

__global__ void k_scan1(const int* __restrict__ deg, int* __restrict__ row_start,
                        int* __restrict__ blk) {
    __shared__ int s[256];
    int i = blockIdx.x * 256 + threadIdx.x;
    int v = (i < NN) ? deg[i] : 0;
    s[threadIdx.x] = v;
    __syncthreads();
    for (int o = 1; o < 256; o <<= 1) {
        int t = (threadIdx.x >= o) ? s[threadIdx.x - o] : 0;
        __syncthreads();
        s[threadIdx.x] += t;
        __syncthreads();
    }
    if (i < NN) row_start[i] = s[threadIdx.x] - v;
    if (threadIdx.x == 255) blk[blockIdx.x] = s[255];
}

__global__ void k_scan2(int* __restrict__ blk, int nb) {
    __shared__ int s[256];
    int v = (threadIdx.x < nb) ? blk[threadIdx.x] : 0;
    s[threadIdx.x] = v;
    __syncthreads();
    for (int o = 1; o < 256; o <<= 1) {
        int t = (threadIdx.x >= o) ? s[threadIdx.x - o] : 0;
        __syncthreads();
        s[threadIdx.x] += t;
        __syncthreads();
    }
    if (threadIdx.x < nb) blk[threadIdx.x] = s[threadIdx.x] - v;
}

__global__ void k_scan3(int* __restrict__ row_start, const int* __restrict__ blk,
                        const int* __restrict__ deg, int* __restrict__ cursor,
                        float* __restrict__ dinv, float* __restrict__ inv_sage) {
    int i = blockIdx.x * 256 + threadIdx.x;
    if (i < NN) {
        int rs = row_start[i] + blk[blockIdx.x];
        row_start[i] = rs;
        cursor[i] = rs;
        int d = deg[i];
        dinv[i] = rsqrtf((float)(d + 1));
        inv_sage[i] = 1.0f / (float)(d > 1 ? d : 1);
    }
}

__global__ void k_fill(const int* __restrict__ ei, int* __restrict__ cursor,
                       int* __restrict__ csr_src) {
    int e = blockIdx.x * 256 + threadIdx.x;
    if (e < EE) {
        int d = ei[EE + e];
        int p = atomicAdd(&cursor[d], 1);
        csr_src[p] = ei[e];
    }
}

// ---------------- fused weight prep ----------------

__device__ __forceinline__ void split_store(float x, size_t dst, short* hi, short* lo) {
    unsigned int ux = __builtin_bit_cast(unsigned int, x);
    unsigned short hx = (unsigned short)(ux >> 16);
    float fx = __builtin_bit_cast(float, ux & 0xffff0000u);
    unsigned short lx = (unsigned short)(__builtin_bit_cast(unsigned int, x - fx) >> 16);
    hi[dst] = (short)hx;
    lo[dst] = (short)lx;
}

__device__ __forceinline__ void prep_one(float x, int k, int n, int cBase,
                                         short* hi, short* lo) {
    int c = (k >> 6) + cBase;
    int s = (k >> 5) & 1, quad = (k >> 3) & 3, j = k & 7;
    int G = n >> 4, l = quad * 16 + (n & 15);
    size_t dst = ((((size_t)(c * 2 + s)) * 8 + G) * 64 + l) * 8 + j;
    split_store(x, dst, hi, lo);
}

__global__ void k_prep_all(const float* __restrict__ W1, const float* __restrict__ Wl,
                           const float* __restrict__ Wr, const float* __restrict__ W3,
                           const float* __restrict__ att_src, const float* __restrict__ att_dst,
                           short* __restrict__ w1hi, short* __restrict__ w1lo,
                           short* __restrict__ wshi, short* __restrict__ wslo,
                           short* __restrict__ w3hi, short* __restrict__ w3lo,
                           float* __restrict__ wsrc, float* __restrict__ wdst) {
    int b = blockIdx.x, tid = threadIdx.x;
    if (b < 64) {
        int i = b * 256 + tid;
        prep_one(W1[i], i >> 7, i & 127, 0, w1hi, w1lo);
    } else if (b < 128) {
        int i = (b - 64) * 256 + tid;
        prep_one(Wl[i], i >> 7, i & 127, 0, wshi, wslo);
    } else if (b < 192) {
        int i = (b - 128) * 256 + tid;
        prep_one(Wr[i], i >> 7, i & 127, 2, wshi, wslo);
    } else if (b < 384) {
        int i = (b - 192) * 256 + tid;
        int k = i >> 7, n = i & 127;
        int h = k >> 7, kk = k & 127;
        float x = W3[(size_t)kk * 384 + h * 128 + n] * (1.f / 3.f);
        prep_one(x, k, n, 0, w3hi, w3lo);
    } else {
        for (int e = tid; e < 384; e += 256) {
            int h = e >> 7, k = e & 127;
            float s1 = 0.f, s2 = 0.f;
            const float* wrow = W3 + (size_t)k * 384 + h * 128;
            const float* as = att_src + h * 128;
            const float* ad = att_dst + h * 128;
            for (int j = 0; j < 128; j++) {
                float wv = wrow[j];
                s1 += wv * as[j];
                s2 += wv * ad[j];
            }
            wsrc[e] = s1;
            wdst[e] = s2;
        }
    }
}

// ---------------- MFMA GEMM, fp32 A via LDS split (layer 1 only) ----------------

__global__ __launch_bounds__(256) void k_gemm_mfma(
    const float* __restrict__ A, const short* __restrict__ Bhi, const short* __restrict__ Blo,
    unsigned short* __restrict__ Cb, int M, int kcT, int strideA) {
    __shared__ short Ahi[128 * 72];
    __shared__ short Alo[128 * 72];
    int tid = threadIdx.x;
    int rBase = blockIdx.x * 128;
    int wv = tid >> 6, lane = tid & 63;
    int rowHalf = wv >> 1, colHalf = wv & 1;
    int quad = lane >> 4, l15 = lane & 15;

    f32x4 acc[4][4];
#pragma unroll
    for (int a = 0; a < 4; a++)
#pragma unroll
        for (int b = 0; b < 4; b++) acc[a][b] = (f32x4)(0.f);

    for (int c = 0; c < kcT; c++) {
        int kOff = c * 64;
        __syncthreads();
#pragma unroll
        for (int q8 = 0; q8 < 8; q8++) {
            int slot = q8 * 256 + tid;
            int r = slot >> 4, k4 = slot & 15;
            float4 v = make_float4(0.f, 0.f, 0.f, 0.f);
            int gr = rBase + r;
            if (gr < M) v = *(const float4*)(A + (size_t)gr * strideA + kOff + k4 * 4);
            unsigned int ux = __builtin_bit_cast(unsigned int, v.x);
            unsigned int uy = __builtin_bit_cast(unsigned int, v.y);
            unsigned int uz = __builtin_bit_cast(unsigned int, v.z);
            unsigned int uw = __builtin_bit_cast(unsigned int, v.w);
            unsigned int hx = ux >> 16, hy = uy >> 16, hz = uz >> 16, hw = uw >> 16;
            float fx = __builtin_bit_cast(float, ux & 0xffff0000u);
            float fy = __builtin_bit_cast(float, uy & 0xffff0000u);
            float fz = __builtin_bit_cast(float, uz & 0xffff0000u);
            float fw = __builtin_bit_cast(float, uw & 0xffff0000u);
            unsigned int lx = __builtin_bit_cast(unsigned int, v.x - fx) >> 16;
            unsigned int ly = __builtin_bit_cast(unsigned int, v.y - fy) >> 16;
            unsigned int lz = __builtin_bit_cast(unsigned int, v.z - fz) >> 16;
            unsigned int lw = __builtin_bit_cast(unsigned int, v.w - fw) >> 16;
            uint2 ph = make_uint2(hx | (hy << 16), hz | (hw << 16));
            uint2 pl = make_uint2(lx | (ly << 16), lz | (lw << 16));
            *(uint2*)(Ahi + r * 72 + k4 * 4) = ph;
            *(uint2*)(Alo + r * 72 + k4 * 4) = pl;
        }
        __syncthreads();

#pragma unroll
        for (int s = 0; s < 2; s++) {
            short8 ah[4], al[4];
#pragma unroll
            for (int rb = 0; rb < 4; rb++) {
                int m = rowHalf * 64 + rb * 16 + l15;
                ah[rb] = *(const short8*)(Ahi + m * 72 + s * 32 + quad * 8);
                al[rb] = *(const short8*)(Alo + m * 72 + s * 32 + quad * 8);
            }
#pragma unroll
            for (int cg = 0; cg < 4; cg++) {
                int G = colHalf * 4 + cg;
                size_t bo = ((((size_t)(c * 2 + s)) * 8 + G) * 64 + lane) * 8;
                short8 bh = *(const short8*)(Bhi + bo);
                short8 bl = *(const short8*)(Blo + bo);
#pragma unroll
                for (int rb = 0; rb < 4; rb++) {
                    acc[rb][cg] = __builtin_amdgcn_mfma_f32_16x16x32_bf16(ah[rb], bh, acc[rb][cg], 0, 0, 0);
                    acc[rb][cg] = __builtin_amdgcn_mfma_f32_16x16x32_bf16(al[rb], bh, acc[rb][cg], 0, 0, 0);
                    acc[rb][cg] = __builtin_amdgcn_mfma_f32_16x16x32_bf16(ah[rb], bl, acc[rb][cg], 0, 0, 0);
                }
            }
        }
    }

#pragma unroll
    for (int cg = 0; cg < 4; cg++) {
        int col = colHalf * 64 + cg * 16 + l15;
#pragma unroll
        for (int rb = 0; rb < 4; rb++) {
#pragma unroll
            for (int r = 0; r < 4; r++) {
                int row = rBase + rowHalf * 64 + rb * 16 + quad * 4 + r;
                if (row < M) Cb[(size_t)row * HH + col] = f2b(acc[rb][cg][r]);
            }
        }
    }
}

// ---------------- MFMA GEMM, bf16 A, barrier-free direct fragment loads ----------
// C = [A1|A2] @ B + bias; A fragments loaded straight from global (16B/lane).

template <bool OUTB, bool STATS>
__global__ __launch_bounds__(256) void k_gemm_direct(
    const unsigned short* __restrict__ A1, const unsigned short* __restrict__ A2,
    const short* __restrict__ Bhi, const short* __restrict__ Blo,
    const float* __restrict__ bias, void* __restrict__ Cv,
    float* __restrict__ sums, int M, int kc1, int kcT, int strideA1) {
    __shared__ float cs[256];
    int tid = threadIdx.x;
    int rBase = blockIdx.x * 128;
    int wv = tid >> 6, lane = tid & 63;
    int rowHalf = wv >> 1, colHalf = wv & 1;
    int quad = lane >> 4, l15 = lane & 15;

    f32x4 acc[4][4];
#pragma unroll
    for (int a = 0; a < 4; a++)
#pragma unroll
        for (int b = 0; b < 4; b++) acc[a][b] = (f32x4)(0.f);

    for (int c = 0; c < kcT; c++) {
        const unsigned short* As;
        int kOff, strideA;
        if (c < kc1) { As = A1; kOff = c * 64; strideA = strideA1; }
        else { As = A2; kOff = (c - kc1) * 64; strideA = 128; }

        // batch all loads for this chunk (no LDS, no barriers)
        short8 a[2][4], bh[2][4], bl[2][4];
#pragma unroll
        for (int s = 0; s < 2; s++) {
#pragma unroll
            for (int rb = 0; rb < 4; rb++) {
                int row = rBase + rowHalf * 64 + rb * 16 + l15;
                int gr = row < M ? row : M - 1;  // clamp; garbage rows discarded at store
                a[s][rb] = *(const short8*)(As + (size_t)gr * strideA + kOff + s * 32 + quad * 8);
            }
#pragma unroll
            for (int cg = 0; cg < 4; cg++) {
                int G = colHalf * 4 + cg;
                size_t bo = ((((size_t)(c * 2 + s)) * 8 + G) * 64 + lane) * 8;
                bh[s][cg] = *(const short8*)(Bhi + bo);
                bl[s][cg] = *(const short8*)(Blo + bo);
            }
        }
#pragma unroll
        for (int s = 0; s < 2; s++) {
#pragma unroll
            for (int cg = 0; cg < 4; cg++) {
#pragma unroll
                for (int rb = 0; rb < 4; rb++) {
                    acc[rb][cg] = __builtin_amdgcn_mfma_f32_16x16x32_bf16(a[s][rb], bh[s][cg], acc[rb][cg], 0, 0, 0);
                    acc[rb][cg] = __builtin_amdgcn_mfma_f32_16x16x32_bf16(a[s][rb], bl[s][cg], acc[rb][cg], 0, 0, 0);
                }
            }
        }
    }

    if (STATS) {
        cs[tid] = 0.f;
        __syncthreads();
    }

#pragma unroll
    for (int cg = 0; cg < 4; cg++) {
        int col = colHalf * 64 + cg * 16 + l15;
        float bv = bias ? bias[col] : 0.f;
        float ps = 0.f, pq = 0.f;
#pragma unroll
        for (int rb = 0; rb < 4; rb++) {
#pragma unroll
            for (int r = 0; r < 4; r++) {
                int row = rBase + rowHalf * 64 + rb * 16 + quad * 4 + r;
                if (row < M) {
                    float ov = acc[rb][cg][r] + bv;
                    if (OUTB) ((unsigned short*)Cv)[(size_t)row * HH + col] = f2b(ov);
                    else ((float*)Cv)[(size_t)row * HH + col] = ov;
                    if (STATS) { ps += ov; pq += ov * ov; }
                }
            }
        }
        if (STATS) {
            ps += __shfl_xor(ps, 16, 64); ps += __shfl_xor(ps, 32, 64);
            pq += __shfl_xor(pq, 16, 64); pq += __shfl_xor(pq, 32, 64);
            if (quad == 0) {
                atomicAdd(&cs[col], ps);
                atomicAdd(&cs[128 + col], pq);
            }
        }
    }
    if (STATS) {
        __syncthreads();
        atomicAdd(&sums[tid], cs[tid]);
    }
}

// ---------------- GCN aggregation (4 nodes/wave, 16 lanes each, uint4 loads) -----

__global__ void k_gcn_agg(const unsigned int* __restrict__ hb, const int* __restrict__ row_start,
                          const int* __restrict__ deg, const int* __restrict__ csr,
                          const float* __restrict__ dinv, const float* __restrict__ b1,
                          unsigned int* __restrict__ outb) {
    int tid = threadIdx.x;
    int n = blockIdx.x * 16 + (tid >> 4);
    if (n >= NN) return;
    int l = tid & 15;
    const uint4* hb4 = (const uint4*)hb;
    float di = dinv[n];
    float wsq = di * di;
    uint4 hv4 = hb4[(size_t)n * 16 + l];
    float2 p0 = b2f2(hv4.x), p1 = b2f2(hv4.y), p2 = b2f2(hv4.z), p3 = b2f2(hv4.w);
    float acc[8] = {p0.x * wsq, p0.y * wsq, p1.x * wsq, p1.y * wsq,
                    p2.x * wsq, p2.y * wsq, p3.x * wsq, p3.y * wsq};
    int s0 = row_start[n], cnt = deg[n];
    int i = 0;
    for (; i + 4 <= cnt; i += 4) {
        int ss[4]; float ww[4]; uint4 vv[4];
#pragma unroll
        for (int j = 0; j < 4; j++) ss[j] = csr[s0 + i + j];
#pragma unroll
        for (int j = 0; j < 4; j++) { ww[j] = dinv[ss[j]]; vv[j] = hb4[(size_t)ss[j] * 16 + l]; }
#pragma unroll
        for (int j = 0; j < 4; j++) {
            float wj = ww[j] * di;
            float2 q0 = b2f2(vv[j].x), q1 = b2f2(vv[j].y), q2 = b2f2(vv[j].z), q3 = b2f2(vv[j].w);
            acc[0] += q0.x * wj; acc[1] += q0.y * wj;
            acc[2] += q1.x * wj; acc[3] += q1.y * wj;
            acc[4] += q2.x * wj; acc[5] += q2.y * wj;
            acc[6] += q3.x * wj; acc[7] += q3.y * wj;
        }
    }
    for (; i < cnt; i++) {
        int s = csr[s0 + i];
        float wj = dinv[s] * di;
        uint4 v = hb4[(size_t)s * 16 + l];
        float2 q0 = b2f2(v.x), q1 = b2f2(v.y), q2 = b2f2(v.z), q3 = b2f2(v.w);
        acc[0] += q0.x * wj; acc[1] += q0.y * wj;
        acc[2] += q1.x * wj; acc[3] += q1.y * wj;
        acc[4] += q2.x * wj; acc[5] += q2.y * wj;
        acc[6] += q3.x * wj; acc[7] += q3.y * wj;
    }
    float4 bb0 = *(const float4*)(b1 + l * 8);
    float4 bb1 = *(const float4*)(b1 + l * 8 + 4);
    uint4 o;
    o.x = pack2(acc[0] + bb0.x, acc[1] + bb0.y);
    o.y = pack2(acc[2] + bb0.z, acc[3] + bb0.w);
    o.z = pack2(acc[4] + bb1.x, acc[5] + bb1.y);
    o.w = pack2(acc[6] + bb1.z, acc[7] + bb1.w);
    ((uint4*)outb)[(size_t)n * 16 + l] = o;
}

// ---------------- BN stats over bf16 array (separate, cheap) ----------------

__global__ void k_bn_stats_b(const unsigned int* __restrict__ hb, float* __restrict__ sums) {
    int f = threadIdx.x;
    int rows_per = (NN + gridDim.x - 1) / gridDim.x;
    int r0 = blockIdx.x * rows_per;
    int r1 = r0 + rows_per;
    if (r1 > NN) r1 = NN;
    int wi = f >> 1, hi = f & 1;
    float s = 0.f, sq = 0.f;
    for (int r = r0; r < r1; r++) {
        float2 vv = b2f2(hb[(size_t)r * 64 + wi]);
        float v = hi ? vv.y : vv.x;
        s += v;
        sq += v * v;
    }
    atomicAdd(&sums[f], s);
    atomicAdd(&sums[128 + f], sq);
}

// ---------------- SAGE aggregation (4 nodes/wave, 16 lanes each, uint4 loads) ----

__global__ void k_sage_agg(const unsigned int* __restrict__ hb, const int* __restrict__ row_start,
                           const int* __restrict__ deg, const int* __restrict__ csr,
                           const float* __restrict__ inv_sage, unsigned int* __restrict__ outb) {
    int tid = threadIdx.x;
    int n = blockIdx.x * 16 + (tid >> 4);
    if (n >= NN) return;
    int l = tid & 15;
    const uint4* hb4 = (const uint4*)hb;
    float acc[8] = {0.f, 0.f, 0.f, 0.f, 0.f, 0.f, 0.f, 0.f};
    int s0 = row_start[n], cnt = deg[n];
    int i = 0;
    for (; i + 4 <= cnt; i += 4) {
        int ss[4]; uint4 vv[4];
#pragma unroll
        for (int j = 0; j < 4; j++) ss[j] = csr[s0 + i + j];
#pragma unroll
        for (int j = 0; j < 4; j++) vv[j] = hb4[(size_t)ss[j] * 16 + l];
#pragma unroll
        for (int j = 0; j < 4; j++) {
            float2 q0 = b2f2(vv[j].x), q1 = b2f2(vv[j].y), q2 = b2f2(vv[j].z), q3 = b2f2(vv[j].w);
            acc[0] += q0.x; acc[1] += q0.y;
            acc[2] += q1.x; acc[3] += q1.y;
            acc[4] += q2.x; acc[5] += q2.y;
            acc[6] += q3.x; acc[7] += q3.y;
        }
    }
    for (; i < cnt; i++) {
        uint4 v = hb4[(size_t)csr[s0 + i] * 16 + l];
        float2 q0 = b2f2(v.x), q1 = b2f2(v.y), q2 = b2f2(v.z), q3 = b2f2(v.w);
        acc[0] += q0.x; acc[1] += q0.y;
        acc[2] += q1.x; acc[3] += q1.y;
        acc[4] += q2.x; acc[5] += q2.y;
        acc[6] += q3.x; acc[7] += q3.y;
    }
    float sc = inv_sage[n];
    uint4 o;
    o.x = pack2(acc[0] * sc, acc[1] * sc);
    o.y = pack2(acc[2] * sc, acc[3] * sc);
    o.z = pack2(acc[4] * sc, acc[5] * sc);
    o.w = pack2(acc[6] * sc, acc[7] * sc);
    ((uint4*)outb)[(size_t)n * 16 + l] = o;
}

// ---------------- GAT: fused softmax + aggregation (2 nodes/wave, fp8, pk-fma) ---

__device__ __forceinline__ float lrelu(float a) { return fmaxf(a, SLOPE * a); }

__global__ void k_gat_fused(const unsigned int* __restrict__ h8u, const int* __restrict__ row_start,
                            const int* __restrict__ deg, const int* __restrict__ csr,
                            const float4* __restrict__ asrc4, const float4* __restrict__ adst4,
                            float4* __restrict__ alphaE, unsigned int* __restrict__ aggb) {
    int tid = threadIdx.x;
    int wv = tid >> 6, lane = tid & 63;
    int half = lane >> 5, l = lane & 31;
    int n = blockIdx.x * 8 + wv * 2 + half;
    if (n >= NN) return;
    float4 ad = adst4[n], asv = asrc4[n];
    float es0 = lrelu(asv.x + ad.x), es1 = lrelu(asv.y + ad.y), es2 = lrelu(asv.z + ad.z);
    int s0 = row_start[n], cnt = deg[n];
    float self0, self1, self2;
    unsigned int pk1 = 0, pk2 = 0;
    bool fast = (cnt <= 32);
    if (fast) {
        bool valid = l < cnt;
        int sReg = 0;
        float e0 = -3e38f, e1 = -3e38f, e2 = -3e38f;
        if (valid) {
            sReg = csr[s0 + l];
            float4 a4 = asrc4[sReg];
            e0 = lrelu(a4.x + ad.x); e1 = lrelu(a4.y + ad.y); e2 = lrelu(a4.z + ad.z);
        }
        float M0 = e0, M1 = e1, M2 = e2;
#pragma unroll
        for (int o = 16; o > 0; o >>= 1) {
            M0 = fmaxf(M0, __shfl_xor(M0, o, 64));
            M1 = fmaxf(M1, __shfl_xor(M1, o, 64));
            M2 = fmaxf(M2, __shfl_xor(M2, o, 64));
        }
        float m0 = fmaxf(es0, M0), m1 = fmaxf(es1, M1), m2 = fmaxf(es2, M2);
        float w0 = valid ? __expf(e0 - m0) : 0.f;
        float w1 = valid ? __expf(e1 - m1) : 0.f;
        float w2 = valid ? __expf(e2 - m2) : 0.f;
        float S0 = w0, S1 = w1, S2 = w2;
#pragma unroll
        for (int o = 16; o > 0; o >>= 1) {
            S0 += __shfl_xor(S0, o, 64);
            S1 += __shfl_xor(S1, o, 64);
            S2 += __shfl_xor(S2, o, 64);
        }
        float sw0 = __expf(es0 - m0), sw1 = __expf(es1 - m1), sw2 = __expf(es2 - m2);
        float r0 = 1.f / (S0 + sw0), r1 = 1.f / (S1 + sw1), r2 = 1.f / (S2 + sw2);
        pk1 = ((unsigned int)sReg & 0xffffu) | ((unsigned int)f2b(w2 * r2) << 16);
        pk2 = pack2(w0 * r0, w1 * r1);
        self0 = sw0 * r0; self1 = sw1 * r1; self2 = sw2 * r2;
    } else {
        float m0 = es0, m1 = es1, m2 = es2;
        for (int base = 0; base < cnt; base += 32) {
            int i2 = base + l;
            float e0 = -3e38f, e1 = -3e38f, e2 = -3e38f;
            if (i2 < cnt) {
                int s = csr[s0 + i2];
                float4 a4 = asrc4[s];
                e0 = lrelu(a4.x + ad.x); e1 = lrelu(a4.y + ad.y); e2 = lrelu(a4.z + ad.z);
                alphaE[s0 + i2] = make_float4(e0, e1, e2, 0.f);
            }
#pragma unroll
            for (int o = 16; o > 0; o >>= 1) {
                e0 = fmaxf(e0, __shfl_xor(e0, o, 64));
                e1 = fmaxf(e1, __shfl_xor(e1, o, 64));
                e2 = fmaxf(e2, __shfl_xor(e2, o, 64));
            }
            m0 = fmaxf(m0, e0); m1 = fmaxf(m1, e1); m2 = fmaxf(m2, e2);
        }
        float l0 = __expf(es0 - m0), l1 = __expf(es1 - m1), l2 = __expf(es2 - m2);
        for (int base = 0; base < cnt; base += 32) {
            int i2 = base + l;
            float w0 = 0.f, w1 = 0.f, w2 = 0.f;
            if (i2 < cnt) {
                float4 e = alphaE[s0 + i2];
                w0 = __expf(e.x - m0); w1 = __expf(e.y - m1); w2 = __expf(e.z - m2);
            }
#pragma unroll
            for (int o = 16; o > 0; o >>= 1) {
                w0 += __shfl_xor(w0, o, 64);
                w1 += __shfl_xor(w1, o, 64);
                w2 += __shfl_xor(w2, o, 64);
            }
            l0 += w0; l1 += w1; l2 += w2;
        }
        float r0 = 1.f / l0, r1 = 1.f / l1, r2 = 1.f / l2;
        self0 = __expf(es0 - m0) * r0;
        self1 = __expf(es1 - m1) * r1;
        self2 = __expf(es2 - m2) * r2;
        for (int base = 0; base < cnt; base += 32) {
            int i2 = base + l;
            if (i2 < cnt) {
                float4 e = alphaE[s0 + i2];
                alphaE[s0 + i2] = make_float4(__expf(e.x - m0) * r0, __expf(e.y - m1) * r1,
                                              __expf(e.z - m2) * r2, 0.f);
            }
        }
    }

    unsigned int hvu = h8u[(size_t)n * 32 + l];
    f32x2 v01 = __builtin_amdgcn_cvt_pk_f32_fp8((int)hvu, false);
    f32x2 v23 = __builtin_amdgcn_cvt_pk_f32_fp8((int)hvu, true);
    f32x2 a0l = v01 * self0, a0h = v23 * self0;
    f32x2 a1l = v01 * self1, a1h = v23 * self1;
    f32x2 a2l = v01 * self2, a2h = v23 * self2;
    int lbase = half << 5;
    if (fast) {
        int i = 0;
        for (; i + 4 <= cnt; i += 4) {
            unsigned int q1[4], q2[4], uu[4];
#pragma unroll
            for (int j = 0; j < 4; j++) {
                q1[j] = __shfl(pk1, lbase + i + j, 64);
                q2[j] = __shfl(pk2, lbase + i + j, 64);
            }
#pragma unroll
            for (int j = 0; j < 4; j++) uu[j] = h8u[(size_t)(q1[j] & 0xffffu) * 32 + l];
#pragma unroll
            for (int j = 0; j < 4; j++) {
                f32x2 w01 = __builtin_amdgcn_cvt_pk_f32_fp8((int)uu[j], false);
                f32x2 w23 = __builtin_amdgcn_cvt_pk_f32_fp8((int)uu[j], true);
                float2 a01 = b2f2(q2[j]);
                float w2 = __builtin_bit_cast(float, q1[j] & 0xffff0000u);
                a0l += a01.x * w01; a0h += a01.x * w23;
                a1l += a01.y * w01; a1h += a01.y * w23;
                a2l += w2 * w01;    a2h += w2 * w23;
            }
        }
        for (; i < cnt; i++) {
            unsigned int q1 = __shfl(pk1, lbase + i, 64);
            unsigned int q2 = __shfl(pk2, lbase + i, 64);
            unsigned int u = h8u[(size_t)(q1 & 0xffffu) * 32 + l];
            f32x2 w01 = __builtin_amdgcn_cvt_pk_f32_fp8((int)u, false);
            f32x2 w23 = __builtin_amdgcn_cvt_pk_f32_fp8((int)u, true);
            float2 a01 = b2f2(q2);
            float w2 = __builtin_bit_cast(float, q1 & 0xffff0000u);
            a0l += a01.x * w01; a0h += a01.x * w23;
            a1l += a01.y * w01; a1h += a01.y * w23;
            a2l += w2 * w01;    a2h += w2 * w23;
        }
    } else {
        for (int i = 0; i < cnt; i++) {
            int s = csr[s0 + i];
            float4 al = alphaE[s0 + i];
            unsigned int u = h8u[(size_t)s * 32 + l];
            f32x2 w01 = __builtin_amdgcn_cvt_pk_f32_fp8((int)u, false);
            f32x2 w23 = __builtin_amdgcn_cvt_pk_f32_fp8((int)u, true);
            a0l += al.x * w01; a0h += al.x * w23;
            a1l += al.y * w01; a1h += al.y * w23;
            a2l += al.z * w01; a2h += al.z * w23;
        }
    }
    unsigned int* op = aggb + (size_t)n * 192 + 2 * l;
    *(uint2*)(op) = make_uint2(pack2(a0l.x, a0l.y), pack2(a0h.x, a0h.y));
    *(uint2*)(op + 64) = make_uint2(pack2(a1l.x, a1l.y), pack2(a1h.x, a1h.y));
    *(uint2*)(op + 128) = make_uint2(pack2(a2l.x, a2l.y), pack2(a2h.x, a2h.y));
}

// ---------------- BatchNorm + ELU ----------------

__device__ __forceinline__ float elu1(float x) { return x > 0.f ? x : (__expf(x) - 1.f); }

__device__ __forceinline__ float4 bn_apply4(float4 v, const float* sums,
                                            const float* gamma, const float* beta, int f4) {
    const float invN = 1.0f / NN;
    float4 s4 = *(const float4*)(sums + f4);
    float4 q4 = *(const float4*)(sums + 128 + f4);
    float4 g4 = *(const float4*)(gamma + f4);
    float4 b4 = *(const float4*)(beta + f4);
    float mx = s4.x * invN, my = s4.y * invN, mz = s4.z * invN, mw = s4.w * invN;
    float scx = rsqrtf(q4.x * invN - mx * mx + EPSV) * g4.x;
    float scy = rsqrtf(q4.y * invN - my * my + EPSV) * g4.y;
    float scz = rsqrtf(q4.z * invN - mz * mz + EPSV) * g4.z;
    float scw = rsqrtf(q4.w * invN - mw * mw + EPSV) * g4.w;
    v.x = elu1(v.x * scx + (b4.x - mx * scx));
    v.y = elu1(v.y * scy + (b4.y - my * scy));
    v.z = elu1(v.z * scz + (b4.z - mz * scz));
    v.w = elu1(v.w * scw + (b4.w - mw * scw));
    return v;
}

__global__ void k_bn_elu_b(const unsigned int* __restrict__ hpre, const float* __restrict__ sums,
                           const float* __restrict__ gamma, const float* __restrict__ beta,
                           unsigned int* __restrict__ hb) {
    int i = blockIdx.x * 256 + threadIdx.x;
    int f4 = (i & 31) << 2;
    uint2 p = *(const uint2*)(hpre + (size_t)(i >> 5) * 64 + (i & 31) * 2);
    float2 v01 = b2f2(p.x), v23 = b2f2(p.y);
    float4 v = make_float4(v01.x, v01.y, v23.x, v23.y);
    v = bn_apply4(v, sums, gamma, beta, f4);
    uint2 q = make_uint2(pack2(v.x, v.y), pack2(v.z, v.w));
    *(uint2*)(hb + (size_t)(i >> 5) * 64 + (i & 31) * 2) = q;
}

__global__ void k_bn_elu_att(const float* __restrict__ h, const float* __restrict__ sums,
                             const float* __restrict__ gamma, const float* __restrict__ beta,
                             const float* __restrict__ wsrc, const float* __restrict__ wdst,
                             unsigned int* __restrict__ h8w, float4* __restrict__ asrc4,
                             float4* __restrict__ adst4) {
    int i = blockIdx.x * 256 + threadIdx.x;
    int fi = i & 31;
    int f4 = fi << 2;
    float4 v = bn_apply4(((const float4*)h)[i], sums, gamma, beta, f4);
    int p8 = __builtin_amdgcn_cvt_pk_fp8_f32(v.x, v.y, 0, false);
    p8 = __builtin_amdgcn_cvt_pk_fp8_f32(v.z, v.w, p8, true);
    h8w[(size_t)(i >> 5) * 32 + fi] = (unsigned int)p8;
    const float4* ws4 = (const float4*)wsrc;
    const float4* wd4 = (const float4*)wdst;
    float d[6];
#pragma unroll
    for (int hd = 0; hd < 3; hd++) {
        float4 a = ws4[hd * 32 + fi];
        float4 b = wd4[hd * 32 + fi];
        d[hd] = v.x * a.x + v.y * a.y + v.z * a.z + v.w * a.w;
        d[3 + hd] = v.x * b.x + v.y * b.y + v.z * b.z + v.w * b.w;
    }
#pragma unroll
    for (int o = 16; o > 0; o >>= 1) {
#pragma unroll
        for (int j = 0; j < 6; j++) d[j] += __shfl_xor(d[j], o, 64);
    }
    if ((threadIdx.x & 31) == 0) {
        int r = i >> 5;
        asrc4[r] = make_float4(d[0], d[1], d[2], 0.f);
        adst4[r] = make_float4(d[3], d[4], d[5], 0.f);
    }
}

// ---------------- Pool (BN+ELU fused, bf16 input) + classifier ----------------

#define POOL_BLOCKS 800

__global__ void k_pool_bn(const unsigned int* __restrict__ hb, const int* __restrict__ batch,
                          const float* __restrict__ sums, const float* __restrict__ gamma,
                          const float* __restrict__ beta, float* __restrict__ pool,
                          float* __restrict__ cntf) {
    const int RP = (NN + POOL_BLOCKS - 1) / POOL_BLOCKS;
    int r0 = blockIdx.x * RP;
    int r1 = r0 + RP;
    if (r1 > NN) r1 = NN;
    if (r0 >= r1) return;
    int f = threadIdx.x;
    const float invN = 1.0f / NN;
    float mu = sums[f] * invN;
    float var = sums[128 + f] * invN - mu * mu;
    float sc = rsqrtf(var + EPSV) * gamma[f];
    float sh = beta[f] - mu * sc;
    int g = batch[r0];
    float s = 0.f, c = 0.f;
    for (int r = r0; r < r1; r++) {
        int gr = batch[r];
        if (gr != g) {
            atomicAdd(&pool[g * 128 + f], s);
            if (f == 0) atomicAdd(&cntf[g], c);
            s = 0.f; c = 0.f; g = gr;
        }
        unsigned int u = hb[(size_t)r * 64 + (f >> 1)];
        float2 vv = b2f2(u);
        float hv = (f & 1) ? vv.y : vv.x;
        s += elu1(hv * sc + sh);
        c += 1.f;
    }
    atomicAdd(&pool[g * 128 + f], s);
    if (f == 0) atomicAdd(&cntf[g], c);
}

__global__ void k_pool_fin(const float* __restrict__ pool, const float* __restrict__ cntf,
                           const float* __restrict__ Wc, const float* __restrict__ bc,
                           float* __restrict__ outp) {
    __shared__ float pr[128];
    int g = blockIdx.x, f = threadIdx.x;
    float c = fmaxf(cntf[g], 1.f);
    float pv = pool[g * 128 + f] / c;
    outp[g * 128 + f] = pv;
    pr[f] = pv;
    __syncthreads();
    if (f < CC) {
        float s = bc[f];
        for (int k = 0; k < 128; k++) s += pr[k] * Wc[k * CC + f];
        outp[GG * HH + g * CC + f] = s;
    }
}

// ---------------- launch ----------------

extern "C" void kernel_launch(void* const* d_in, const int* in_sizes, int n_in,
                              void* d_out, int out_size, void* d_ws, size_t ws_size,
                              hipStream_t stream) {
    const float* x = (const float*)d_in[0];
    const int* ei = (const int*)d_in[1];
    const int* batch = (const int*)d_in[2];
    const float* W1 = (const float*)d_in[3];
    const float* b1 = (const float*)d_in[4];
    const float* gamma1 = (const float*)d_in[5];
    const float* beta1 = (const float*)d_in[6];
    const float* Wl = (const float*)d_in[7];
    const float* bl = (const float*)d_in[8];
    const float* Wr = (const float*)d_in[9];
    const float* gamma2 = (const float*)d_in[10];
    const float* beta2 = (const float*)d_in[11];
    const float* W3 = (const float*)d_in[12];
    const float* att_src = (const float*)d_in[13];
    const float* att_dst = (const float*)d_in[14];
    const float* b3 = (const float*)d_in[15];
    const float* gamma3 = (const float*)d_in[16];
    const float* beta3 = (const float*)d_in[17];
    const float* Wc = (const float*)d_in[18];
    const float* bc = (const float*)d_in[19];

    char* w = (char*)d_ws;
    size_t o = 0;
    float* bufC = (float*)(w + o); o += (size_t)NN * 128 * 4;
    unsigned int* h0b = (unsigned int*)(w + o); o += (size_t)NN * 128 * 2;
    unsigned int* h1pre = (unsigned int*)(w + o); o += (size_t)NN * 128 * 2;
    unsigned int* h1b = (unsigned int*)(w + o); o += (size_t)NN * 128 * 2;
    unsigned int* sageb = (unsigned int*)(w + o); o += (size_t)NN * 128 * 2;
    unsigned int* h2f8 = (unsigned int*)(w + o); o += (size_t)NN * 128;
    unsigned int* aggDb = (unsigned int*)(w + o); o += (size_t)NN * 384 * 2;
    unsigned int* h3b = (unsigned int*)(w + o); o += (size_t)NN * 128 * 2;
    int* csr = (int*)(w + o); o += (size_t)EE * 4;
    int* deg = (int*)(w + o); o += (size_t)NN * 4;
    int* row_start = (int*)(w + o); o += (size_t)NN * 4;
    int* cursor = (int*)(w + o); o += (size_t)NN * 4;
    float* dinv = (float*)(w + o); o += (size_t)NN * 4;
    float* inv_sage = (float*)(w + o); o += (size_t)NN * 4;
    float4* asrc4 = (float4*)(w + o); o += (size_t)NN * 16;
    float4* adst4 = (float4*)(w + o); o += (size_t)NN * 16;
    float* bn1 = (float*)(w + o); o += 256 * 4;
    float* bn_sums23 = (float*)(w + o); o += 512 * 4;
    int* blk = (int*)(w + o); o += 1024;
    float* poolacc = (float*)(w + o); o += (size_t)GG * 128 * 4;
    float* cntf = (float*)(w + o); o += (size_t)GG * 4;
    float* wsrc = (float*)(w + o); o += 384 * 4;
    float* wdst = (float*)(w + o); o += 384 * 4;
    float4* alphaE = (float4*)(w + o); o += (size_t)EE * 16;
    short* w1hi = (short*)(w + o); o += (size_t)128 * 128 * 2;
    short* w1lo = (short*)(w + o); o += (size_t)128 * 128 * 2;
    short* wshi = (short*)(w + o); o += (size_t)256 * 128 * 2;
    short* wslo = (short*)(w + o); o += (size_t)256 * 128 * 2;
    short* w3hi = (short*)(w + o); o += (size_t)384 * 128 * 2;
    short* w3lo = (short*)(w + o); o += (size_t)384 * 128 * 2;

    float* outp = (float*)d_out;

    const int NB_SCAN = (NN + 255) / 256;
    const int EB = (EE + 255) / 256;
    const int NG8 = (NN + 7) / 8;
    const int NG16 = (NN + 15) / 16;
    const int GB = (NN + 127) / 128;

    k_zero<<<NB_SCAN, 256, 0, stream>>>(deg, bn1, bn_sums23, poolacc);
    k_count_deg<<<EB, 256, 0, stream>>>(ei, deg);
    k_scan1<<<NB_SCAN, 256, 0, stream>>>(deg, row_start, blk);
    k_scan2<<<1, 256, 0, stream>>>(blk, NB_SCAN);
    k_scan3<<<NB_SCAN, 256, 0, stream>>>(row_start, blk, deg, cursor, dinv, inv_sage);
    k_fill<<<EB, 256, 0, stream>>>(ei, cursor, csr);
    k_prep_all<<<385, 256, 0, stream>>>(W1, Wl, Wr, W3, att_src, att_dst, w1hi, w1lo,
                                        wshi, wslo, w3hi, w3lo, wsrc, wdst);

    // Layer 1: GCN (fp32-A LDS GEMM)
    k_gemm_mfma<<<GB, 256, 0, stream>>>(x, w1hi, w1lo, (unsigned short*)h0b, NN, 2, 128);
    k_gcn_agg<<<NG16, 256, 0, stream>>>(h0b, row_start, deg, csr, dinv, b1, h1pre);
    k_bn_stats_b<<<1024, 128, 0, stream>>>(h1pre, bn1);
    k_bn_elu_b<<<NN * 32 / 256, 256, 0, stream>>>(h1pre, bn1, gamma1, beta1, h1b);

    // Layer 2: SAGE (barrier-free direct GEMM, K=256, stats in epilogue)
    k_sage_agg<<<NG16, 256, 0, stream>>>(h1b, row_start, deg, csr, inv_sage, sageb);
    k_gemm_direct<false, true><<<GB, 256, 0, stream>>>(
        (const unsigned short*)sageb, (const unsigned short*)h1b, wshi, wslo, bl, bufC,
        bn_sums23, NN, 2, 4, 128);
    k_bn_elu_att<<<NN * 32 / 256, 256, 0, stream>>>(bufC, bn_sums23, gamma2, beta2,
                                                    wsrc, wdst, h2f8, asrc4, adst4);

    // Layer 3: GAT (barrier-free direct GEMM, K=384)
    k_gat_fused<<<NG8, 256, 0, stream>>>(h2f8, row_start, deg, csr, asrc4, adst4, alphaE, aggDb);
    k_gemm_direct<true, true><<<GB, 256, 0, stream>>>(
        (const unsigned short*)aggDb, nullptr, w3hi, w3lo, b3, h3b,
        bn_sums23 + 256, NN, 6, 6, 384);

    // Pool + classifier
    k_pool_bn<<<POOL_BLOCKS, 128, 0, stream>>>(h3b, batch, bn_sums23 + 256, gamma3, beta3,
                                               poolacc, cntf);
    k_pool_fin<<<GG, 128, 0, stream>>>(poolacc, cntf, Wc, bc, outp);
}